// Round 1
// baseline (1363.320 us; speedup 1.0000x reference)
//
#include <hip/hip_runtime.h>
#include <math.h>

// Problem constants
#define BB   2
#define CSN  128     // src channels
#define CDN  128     // dst/out channels
#define SD   8
#define SH   16
#define SW   16
#define DD   16
#define DH   32
#define DW   32
#define PP   (DD*DH*DW)   // 16384
#define GG   8
#define CGRP 16           // channels per group
#define K3   27
#define OO   648          // K3*3*G

// ---------------------------------------------------------------------------
// Kernel 1: trilinear upsample (half-pixel, edge-clamped == jax.image.resize)
// writes up_std [b][c][p]  and  up_cl [b][g][p][cc] (channel-last per group)
// ---------------------------------------------------------------------------
__global__ __launch_bounds__(256) void upsample_kernel(
    const float* __restrict__ src, float* __restrict__ up_std,
    float* __restrict__ up_cl)
{
    const int idx = blockIdx.x * 256 + threadIdx.x;   // (b*CS + c)*PP + p
    const int p  = idx & (PP - 1);
    const int bc = idx >> 14;
    const int c  = bc & 127;
    const int b  = bc >> 7;
    const int zo = p >> 10, yo = (p >> 5) & 31, xo = p & 31;

    const float sz = 0.5f * (float)zo - 0.25f;
    const float sy = 0.5f * (float)yo - 0.25f;
    const float sx = 0.5f * (float)xo - 0.25f;
    const float zf = floorf(sz), yf = floorf(sy), xf = floorf(sx);
    const float fz = sz - zf, fy = sy - yf, fx = sx - xf;
    int z0 = (int)zf, y0 = (int)yf, x0 = (int)xf;
    int z1 = min(z0 + 1, SD - 1); z0 = max(z0, 0);
    int y1 = min(y0 + 1, SH - 1); y0 = max(y0, 0);
    int x1 = min(x0 + 1, SW - 1); x0 = max(x0, 0);

    const float* s = src + (size_t)(b * CSN + c) * (SD * SH * SW);
    const float v000 = s[(z0 * SH + y0) * SW + x0];
    const float v001 = s[(z0 * SH + y0) * SW + x1];
    const float v010 = s[(z0 * SH + y1) * SW + x0];
    const float v011 = s[(z0 * SH + y1) * SW + x1];
    const float v100 = s[(z1 * SH + y0) * SW + x0];
    const float v101 = s[(z1 * SH + y0) * SW + x1];
    const float v110 = s[(z1 * SH + y1) * SW + x0];
    const float v111 = s[(z1 * SH + y1) * SW + x1];

    const float c00 = v000 + fx * (v001 - v000);
    const float c01 = v010 + fx * (v011 - v010);
    const float c10 = v100 + fx * (v101 - v100);
    const float c11 = v110 + fx * (v111 - v110);
    const float c0  = c00 + fy * (c01 - c00);
    const float c1  = c10 + fy * (c11 - c10);
    const float val = c0 + fz * (c1 - c0);

    up_std[idx] = val;
    const int g = c >> 4, cc = c & 15;
    up_cl[((size_t)(b * GG + g) * PP + p) * CGRP + cc] = val;
}

// ---------------------------------------------------------------------------
// Kernel 2: 1x1 offset conv.  offs[b][o][p] = sum_c w[o][c]*cat[b][c][p]
// cat = [dst (128), 2*up (128)].  4 outputs o per block, weights scalarized.
// ---------------------------------------------------------------------------
__global__ __launch_bounds__(256) void offset_gemm_kernel(
    const float* __restrict__ dst, const float* __restrict__ up_std,
    const float* __restrict__ wof, float* __restrict__ offs)
{
    const int p  = blockIdx.x * 256 + threadIdx.x;
    const int o0 = blockIdx.y * 4;
    const int b  = blockIdx.z;
    const float* w0 = wof + (size_t)o0 * 256;
    const float* d  = dst    + (size_t)b * CDN * PP + p;
    const float* u  = up_std + (size_t)b * CSN * PP + p;

    float a0 = 0.f, a1 = 0.f, a2 = 0.f, a3 = 0.f;
#pragma unroll 8
    for (int c = 0; c < 128; ++c) {
        const float v = d[(size_t)c * PP];
        a0 = fmaf(w0[c],       v, a0);
        a1 = fmaf(w0[256 + c], v, a1);
        a2 = fmaf(w0[512 + c], v, a2);
        a3 = fmaf(w0[768 + c], v, a3);
    }
#pragma unroll 8
    for (int c = 0; c < 128; ++c) {
        const float v = 2.0f * u[(size_t)c * PP];
        a0 = fmaf(w0[128 + c],       v, a0);
        a1 = fmaf(w0[256 + 128 + c], v, a1);
        a2 = fmaf(w0[512 + 128 + c], v, a2);
        a3 = fmaf(w0[768 + 128 + c], v, a3);
    }
    float* op = offs + (size_t)(b * OO + o0) * PP + p;
    op[0]      = a0;
    op[PP]     = a1;
    op[2 * PP] = a2;
    op[3 * PP] = a3;
}

// ---------------------------------------------------------------------------
// Kernel 3: transpose w_dcn [o][c][k] -> wt [k][c][o]
// ---------------------------------------------------------------------------
__global__ __launch_bounds__(256) void wt_kernel(
    const float* __restrict__ wdcn, float* __restrict__ wt)
{
    const int idx = blockIdx.x * 256 + threadIdx.x;  // (k*128 + c)*128 + o
    const int o = idx & 127;
    const int c = (idx >> 7) & 127;
    const int k = idx >> 14;
    wt[idx] = wdcn[((size_t)(o * CSN + c)) * K3 + k];
}

// ---------------------------------------------------------------------------
// Kernel 4: fused deformable sampling + contraction + ReLU.
// One block = (batch b, 64-point tile). Per tap: fill samp[128][64] in LDS,
// then 128x64 register-tiled outer product (8 o x 4 p per thread).
// ---------------------------------------------------------------------------
__global__ __launch_bounds__(256) void fused_kernel(
    const float* __restrict__ up_cl, const float* __restrict__ offs,
    const float* __restrict__ wt, float* __restrict__ out)
{
    __shared__ float samp[CSN * 64];
    const int b   = blockIdx.y;
    const int p0  = blockIdx.x * 64;
    const int tid = threadIdx.x;
    const int tx  = tid & 15;      // point quad: p = p0 + tx*4 + i
    const int ty  = tid >> 4;      // output row block: o = ty*8 + j

    float acc[8][4];
#pragma unroll
    for (int j = 0; j < 8; ++j)
#pragma unroll
        for (int i = 0; i < 4; ++i) acc[j][i] = 0.f;

#pragma unroll 1
    for (int k = 0; k < K3; ++k) {
        const int kz = k / 9 - 1;
        const int ky = (k / 3) % 3 - 1;
        const int kx = (k % 3) - 1;

        // ---- sampling phase: 512 (g,tp) tasks, 2 per thread ----
#pragma unroll
        for (int it = 0; it < 2; ++it) {
            const int task = tid + 256 * it;
            const int g  = task >> 6;
            const int tp = task & 63;
            const int p  = p0 + tp;
            const int zo = p >> 10, yo = (p >> 5) & 31, xo = p & 31;
            const size_t ob = (size_t)(b * OO + g * 81 + k * 3) * PP + p;
            const float z = (float)(zo + kz) + offs[ob];
            const float y = (float)(yo + ky) + offs[ob + PP];
            const float x = (float)(xo + kx) + offs[ob + 2 * PP];
            const float zf = floorf(z), yf = floorf(y), xf = floorf(x);
            const float fz = z - zf, fy = y - yf, fx = x - xf;
            const int z0 = (int)zf, y0 = (int)yf, x0 = (int)xf;

            float a16[16];
#pragma unroll
            for (int cc = 0; cc < 16; ++cc) a16[cc] = 0.f;

            const float* base = up_cl + ((size_t)(b * GG + g) << 18); // *PP*16
#pragma unroll
            for (int dz = 0; dz < 2; ++dz) {
                const int iz = z0 + dz;
                const float wz = dz ? fz : 1.f - fz;
                if (iz < 0 || iz >= DD) continue;
#pragma unroll
                for (int dy = 0; dy < 2; ++dy) {
                    const int iy = y0 + dy;
                    const float wzy = (dy ? fy : 1.f - fy) * wz;
                    if (iy < 0 || iy >= DH) continue;
#pragma unroll
                    for (int dx = 0; dx < 2; ++dx) {
                        const int ix = x0 + dx;
                        if (ix < 0 || ix >= DW) continue;
                        const float w = (dx ? fx : 1.f - fx) * wzy;
                        const float* sp =
                            base + ((size_t)(((iz << 10) + (iy << 5) + ix)) << 4);
                        const float4 v0 = *(const float4*)(sp);
                        const float4 v1 = *(const float4*)(sp + 4);
                        const float4 v2 = *(const float4*)(sp + 8);
                        const float4 v3 = *(const float4*)(sp + 12);
                        const float vv[16] = {v0.x, v0.y, v0.z, v0.w,
                                              v1.x, v1.y, v1.z, v1.w,
                                              v2.x, v2.y, v2.z, v2.w,
                                              v3.x, v3.y, v3.z, v3.w};
#pragma unroll
                        for (int cc = 0; cc < 16; ++cc)
                            a16[cc] = fmaf(w, vv[cc], a16[cc]);
                    }
                }
            }
#pragma unroll
            for (int cc = 0; cc < 16; ++cc)
                samp[(g * CGRP + cc) * 64 + tp] = a16[cc];
        }
        __syncthreads();

        // ---- contraction phase ----
        const float* wk = wt + (size_t)k * CSN * CDN + ty * 8;
#pragma unroll 8
        for (int c = 0; c < CSN; ++c) {
            const float4 s4 = *(const float4*)&samp[c * 64 + tx * 4];
            const float* wr = wk + c * CDN;
            const float4 w0 = *(const float4*)(wr);
            const float4 w1 = *(const float4*)(wr + 4);
            const float wv[8] = {w0.x, w0.y, w0.z, w0.w, w1.x, w1.y, w1.z, w1.w};
            const float sv[4] = {s4.x, s4.y, s4.z, s4.w};
#pragma unroll
            for (int j = 0; j < 8; ++j)
#pragma unroll
                for (int i = 0; i < 4; ++i)
                    acc[j][i] = fmaf(wv[j], sv[i], acc[j][i]);
        }
        __syncthreads();
    }

    // epilogue: ReLU + coalesced float4 stores
#pragma unroll
    for (int j = 0; j < 8; ++j) {
        float4 r;
        r.x = fmaxf(acc[j][0], 0.f);
        r.y = fmaxf(acc[j][1], 0.f);
        r.z = fmaxf(acc[j][2], 0.f);
        r.w = fmaxf(acc[j][3], 0.f);
        *(float4*)(out + (size_t)(b * CDN + ty * 8 + j) * PP + p0 + tx * 4) = r;
    }
}

// ---------------------------------------------------------------------------
extern "C" void kernel_launch(void* const* d_in, const int* in_sizes, int n_in,
                              void* d_out, int out_size, void* d_ws, size_t ws_size,
                              hipStream_t stream)
{
    const float* src1x = (const float*)d_in[0];   // [2,128,8,16,16]
    const float* dst2x = (const float*)d_in[1];   // [2,128,16,32,32]
    const float* w_off = (const float*)d_in[2];   // [648,256]
    const float* w_dcn = (const float*)d_in[3];   // [128,128,3,3,3]
    float* out = (float*)d_out;

    char* ws = (char*)d_ws;
    float* up_std = (float*)(ws);                  // 16,777,216 B
    float* up_cl  = (float*)(ws + 16777216);       // 16,777,216 B
    float* wt     = (float*)(ws + 33554432);       //  1,769,472 B
    float* offs   = (float*)(ws + 35323904);       // 84,934,656 B

    upsample_kernel<<<dim3((BB * CSN * PP) / 256), dim3(256), 0, stream>>>(
        src1x, up_std, up_cl);
    wt_kernel<<<dim3((K3 * CSN * CDN) / 256), dim3(256), 0, stream>>>(w_dcn, wt);
    offset_gemm_kernel<<<dim3(PP / 256, OO / 4, BB), dim3(256), 0, stream>>>(
        dst2x, up_std, w_off, offs);
    fused_kernel<<<dim3(PP / 64, BB), dim3(256), 0, stream>>>(
        up_cl, offs, wt, out);
}

// Round 2
// 355.566 us; speedup vs baseline: 3.8342x; 3.8342x over previous
//
#include <hip/hip_runtime.h>
#include <hip/hip_fp16.h>
#include <math.h>

// Problem constants
#define BB   2
#define CSN  128
#define CDN  128
#define SD   8
#define SH   16
#define SW   16
#define DD   16
#define DH   32
#define DW   32
#define PP   (DD*DH*DW)   // 16384
#define GG   8
#define K3   27
#define OO   648          // K3*3*G
#define MT   41           // o-tiles (16) for offset GEMM, M padded 648->656

typedef _Float16 half8 __attribute__((ext_vector_type(8)));
typedef float f32x4 __attribute__((ext_vector_type(4)));

// ---------------------------------------------------------------------------
// Kernel 1: trilinear upsample -> f16 channel-last  uph[b][g][p][16cc]
// thread = (b,g,p,chpair). Coalesced 4B __half2 stores.
// ---------------------------------------------------------------------------
__global__ __launch_bounds__(256) void up_half_kernel(
    const float* __restrict__ src, __half2* __restrict__ uph)
{
    const int idx = blockIdx.x * 256 + threadIdx.x; // ((b*8+g)*PP+p)*8+ch
    const int ch = idx & 7;
    const int p  = (idx >> 3) & (PP - 1);
    const int bg = idx >> 17;
    const int g  = bg & 7, b = bg >> 3;
    const int zo = p >> 10, yo = (p >> 5) & 31, xo = p & 31;

    const float sz = 0.5f * (float)zo - 0.25f;
    const float sy = 0.5f * (float)yo - 0.25f;
    const float sx = 0.5f * (float)xo - 0.25f;
    const float zf = floorf(sz), yf = floorf(sy), xf = floorf(sx);
    const float fz = sz - zf, fy = sy - yf, fx = sx - xf;
    int z0 = (int)zf, y0 = (int)yf, x0 = (int)xf;
    int z1 = min(z0 + 1, SD - 1); z0 = max(z0, 0);
    int y1 = min(y0 + 1, SH - 1); y0 = max(y0, 0);
    int x1 = min(x0 + 1, SW - 1); x0 = max(x0, 0);

    const int c = g * 16 + ch * 2;
    float v[2];
#pragma unroll
    for (int cc = 0; cc < 2; ++cc) {
        const float* s = src + (size_t)(b * CSN + c + cc) * (SD * SH * SW);
        const float v000 = s[(z0 * SH + y0) * SW + x0];
        const float v001 = s[(z0 * SH + y0) * SW + x1];
        const float v010 = s[(z0 * SH + y1) * SW + x0];
        const float v011 = s[(z0 * SH + y1) * SW + x1];
        const float v100 = s[(z1 * SH + y0) * SW + x0];
        const float v101 = s[(z1 * SH + y0) * SW + x1];
        const float v110 = s[(z1 * SH + y1) * SW + x0];
        const float v111 = s[(z1 * SH + y1) * SW + x1];
        const float c00 = v000 + fx * (v001 - v000);
        const float c01 = v010 + fx * (v011 - v010);
        const float c10 = v100 + fx * (v101 - v100);
        const float c11 = v110 + fx * (v111 - v110);
        const float c0  = c00 + fy * (c01 - c00);
        const float c1  = c10 + fy * (c11 - c10);
        v[cc] = c0 + fz * (c1 - c0);
    }
    uph[idx] = __floats2half2_rn(v[0], v[1]);
}

// ---------------------------------------------------------------------------
// Kernel 2: pack w_offset -> wox f16 A-fragments, M padded to 656, x2 fold for
// the upsampled half of cat.  layout half8 idx = (c0*656 + o)*4 + q
// ---------------------------------------------------------------------------
__global__ __launch_bounds__(256) void pack_wox_kernel(
    const float* __restrict__ wof, half8* __restrict__ wox)
{
    const int idx = blockIdx.x * 256 + threadIdx.x;   // 8*656*4 = 20992 total
    const int q = idx & 3;
    const int rest = idx >> 2;
    const int o = rest % 656;
    const int c0 = rest / 656;
    half8 h;
    if (o < OO) {
        const int c = c0 * 32 + q * 8;
        const float sc = (c >= 128) ? 2.0f : 1.0f;
        const float* wr = wof + (size_t)o * 256 + c;
#pragma unroll
        for (int j = 0; j < 8; ++j) h[j] = (_Float16)(wr[j] * sc);
    } else {
#pragma unroll
        for (int j = 0; j < 8; ++j) h[j] = (_Float16)0.0f;
    }
    wox[idx] = h;
}

// ---------------------------------------------------------------------------
// Kernel 3: pack w_dcn -> wtx f16 A-fragments per tap.
// layout half8 idx = ((k*4 + c0)*128 + o)*4 + q ; value = w_dcn[o][c0*32+q*8+j][k]
// ---------------------------------------------------------------------------
__global__ __launch_bounds__(256) void pack_wtx_kernel(
    const float* __restrict__ wdcn, half8* __restrict__ wtx)
{
    const int idx = blockIdx.x * 256 + threadIdx.x;   // 27*4*128*4 = 55296
    const int q  = idx & 3;
    const int o  = (idx >> 2) & 127;
    const int kc = idx >> 9;
    const int c0 = kc & 3;
    const int k  = kc >> 2;
    const int c  = c0 * 32 + q * 8;
    const float* wr = wdcn + ((size_t)o * CSN + c) * K3 + k;
    half8 h;
#pragma unroll
    for (int j = 0; j < 8; ++j) h[j] = (_Float16)wr[(size_t)j * K3];
    wtx[idx] = h;
}

// ---------------------------------------------------------------------------
// Kernel 4: offset 1x1 conv as f16 MFMA GEMM.  C[o 648][p 64-tile] per block.
// cat staged in LDS in B-fragment layout; wave w owns p-subtile w.
// ---------------------------------------------------------------------------
__global__ __launch_bounds__(256) void offset_mfma_kernel(
    const float* __restrict__ dst, const __half2* __restrict__ uph,
    const half8* __restrict__ wox, float* __restrict__ offs)
{
    __shared__ half8 catx[32 * 64];    // [c-octet 32][p 64] -> 32 KiB
    const int tid = threadIdx.x;
    const int b = blockIdx.y;
    const int p0 = blockIdx.x * 64;

    // ---- stage cat tile (f16) ----
#pragma unroll
    for (int it = 0; it < 2; ++it) {
        const int t = tid + 256 * it;
        const int co = t >> 4, pq = t & 15;
        const int p = p0 + pq * 4;
        if (co < 16) {                       // dst rows, fp32 -> f16
            const int c = co * 8;
            const float* dp = dst + ((size_t)(b * CDN + c) << 14) + p;
            float vv[32];
#pragma unroll
            for (int j = 0; j < 8; ++j)
                *(float4*)&vv[j * 4] = *(const float4*)(dp + ((size_t)j << 14));
#pragma unroll
            for (int i = 0; i < 4; ++i) {
                half8 h;
#pragma unroll
                for (int j = 0; j < 8; ++j) h[j] = (_Float16)vv[j * 4 + i];
                catx[co * 64 + pq * 4 + i] = h;
            }
        } else {                             // upsampled rows: straight f16 copy
            const int g = (co - 16) >> 1, oct = (co - 16) & 1;
            const half8* up8 = (const half8*)uph;
            const size_t base = ((size_t)(b * GG + g) << 14);
#pragma unroll
            for (int i = 0; i < 4; ++i)
                catx[co * 64 + pq * 4 + i] = up8[(base + p + i) * 2 + oct];
        }
    }
    __syncthreads();

    const int w = tid >> 6, l = tid & 63, lo = l & 15, q = l >> 4;

    // B fragments for this wave's p-subtile, all 8 K-chunks
    half8 Bf[8];
#pragma unroll
    for (int c0 = 0; c0 < 8; ++c0)
        Bf[c0] = catx[(c0 * 4 + q) * 64 + w * 16 + lo];

    const int p = p0 + w * 16 + lo;
#pragma unroll 1
    for (int ot2 = 0; ot2 < 21; ++ot2) {
        const int ota = ot2 * 2, otb = ota + 1;
        f32x4 aA = {0.f, 0.f, 0.f, 0.f}, aB = {0.f, 0.f, 0.f, 0.f};
#pragma unroll
        for (int c0 = 0; c0 < 8; ++c0) {
            const half8 Aa = wox[(size_t)(c0 * 656 + ota * 16 + lo) * 4 + q];
            aA = __builtin_amdgcn_mfma_f32_16x16x32_f16(Aa, Bf[c0], aA, 0, 0, 0);
            if (otb < MT) {
                const half8 Ab = wox[(size_t)(c0 * 656 + otb * 16 + lo) * 4 + q];
                aB = __builtin_amdgcn_mfma_f32_16x16x32_f16(Ab, Bf[c0], aB, 0, 0, 0);
            }
        }
#pragma unroll
        for (int r = 0; r < 4; ++r) {
            const int o = ota * 16 + q * 4 + r;
            if (o < OO) offs[((size_t)(b * OO + o) << 14) + p] = aA[r];
        }
        if (otb < MT) {
#pragma unroll
            for (int r = 0; r < 4; ++r) {
                const int o = otb * 16 + q * 4 + r;
                if (o < OO) offs[((size_t)(b * OO + o) << 14) + p] = aB[r];
            }
        }
    }
}

// ---------------------------------------------------------------------------
// Kernel 5: fused deformable sampling (pk-f16 interp) + MFMA contraction + ReLU
// Block = (b, 64-p tile).  Wave w owns o-tiles {2w, 2w+1}, all 4 p-subtiles.
// ---------------------------------------------------------------------------
__global__ __launch_bounds__(256) void fused_mfma_kernel(
    const __half2* __restrict__ uph, const float* __restrict__ offs,
    const half8* __restrict__ wtx, float* __restrict__ out)
{
    __shared__ half8 sampx[16 * 64];   // [c-octet 16][p 64] -> 16 KiB
    const int tid = threadIdx.x;
    const int b = blockIdx.y;
    const int p0 = blockIdx.x * 64;
    const int w = tid >> 6, l = tid & 63, lo = l & 15, q = l >> 4;

    f32x4 acc[2][4];
#pragma unroll
    for (int j = 0; j < 2; ++j)
#pragma unroll
        for (int pt = 0; pt < 4; ++pt) acc[j][pt] = (f32x4){0.f, 0.f, 0.f, 0.f};

#pragma unroll 1
    for (int k = 0; k < K3; ++k) {
        const int kz = k / 9 - 1;
        const int ky = (k / 3) % 3 - 1;
        const int kx = (k % 3) - 1;

        // ---- sampling: 512 (g,tp) tasks, interp in packed f16 ----
#pragma unroll
        for (int it = 0; it < 2; ++it) {
            const int t = tid + 256 * it;
            const int g = t >> 6, tp = t & 63;
            const int p = p0 + tp;
            const int zo = p >> 10, yo = (p >> 5) & 31, xo = p & 31;
            const size_t ob = ((size_t)(b * OO + g * 81 + k * 3) << 14) + p;
            const float z = (float)(zo + kz) + offs[ob];
            const float y = (float)(yo + ky) + offs[ob + PP];
            const float x = (float)(xo + kx) + offs[ob + 2 * PP];
            const float zf = floorf(z), yf = floorf(y), xf = floorf(x);
            const float fz = z - zf, fy = y - yf, fx = x - xf;
            const int z0 = (int)zf, y0 = (int)yf, x0 = (int)xf;

            __align__(16) __half2 acch[8];
#pragma unroll
            for (int r = 0; r < 8; ++r) acch[r] = __floats2half2_rn(0.f, 0.f);

            const float4* base4 =
                (const float4*)(uph + (((size_t)(b * GG + g) << 14) << 3));
#pragma unroll
            for (int dz = 0; dz < 2; ++dz) {
                const int iz = z0 + dz;
                const float wz = dz ? fz : 1.f - fz;
                if (iz < 0 || iz >= DD) continue;
#pragma unroll
                for (int dy = 0; dy < 2; ++dy) {
                    const int iy = y0 + dy;
                    const float wzy = (dy ? fy : 1.f - fy) * wz;
                    if (iy < 0 || iy >= DH) continue;
#pragma unroll
                    for (int dx = 0; dx < 2; ++dx) {
                        const int ix = x0 + dx;
                        if (ix < 0 || ix >= DW) continue;
                        const float wc = (dx ? fx : 1.f - fx) * wzy;
                        const int vox = (iz << 10) + (iy << 5) + ix;
                        float4 u0 = base4[(size_t)vox * 2];
                        float4 u1 = base4[(size_t)vox * 2 + 1];
                        const __half2 wh = __float2half2_rn(wc);
                        const __half2* h0 = (const __half2*)&u0;
                        const __half2* h1 = (const __half2*)&u1;
#pragma unroll
                        for (int r = 0; r < 4; ++r)
                            acch[r] = __hfma2(h0[r], wh, acch[r]);
#pragma unroll
                        for (int r = 0; r < 4; ++r)
                            acch[4 + r] = __hfma2(h1[r], wh, acch[4 + r]);
                    }
                }
            }
            sampx[(g * 2 + 0) * 64 + tp] = *(half8*)&acch[0];
            sampx[(g * 2 + 1) * 64 + tp] = *(half8*)&acch[4];
        }
        __syncthreads();

        // ---- MFMA contraction for this tap ----
#pragma unroll
        for (int c0 = 0; c0 < 4; ++c0) {
            const half8 Aa =
                wtx[(size_t)((k * 4 + c0) * 128 + (2 * w) * 16 + lo) * 4 + q];
            const half8 Ab =
                wtx[(size_t)((k * 4 + c0) * 128 + (2 * w + 1) * 16 + lo) * 4 + q];
#pragma unroll
            for (int pt = 0; pt < 4; ++pt) {
                const half8 Bf = sampx[(c0 * 4 + q) * 64 + pt * 16 + lo];
                acc[0][pt] = __builtin_amdgcn_mfma_f32_16x16x32_f16(Aa, Bf, acc[0][pt], 0, 0, 0);
                acc[1][pt] = __builtin_amdgcn_mfma_f32_16x16x32_f16(Ab, Bf, acc[1][pt], 0, 0, 0);
            }
        }
        __syncthreads();
    }

    // ---- epilogue: ReLU + store ----
#pragma unroll
    for (int j = 0; j < 2; ++j) {
        const int o = (2 * w + j) * 16 + q * 4;
#pragma unroll
        for (int pt = 0; pt < 4; ++pt) {
#pragma unroll
            for (int r = 0; r < 4; ++r)
                out[((size_t)(b * CDN + o + r) << 14) + p0 + pt * 16 + lo] =
                    fmaxf(acc[j][pt][r], 0.f);
        }
    }
}

// ---------------------------------------------------------------------------
extern "C" void kernel_launch(void* const* d_in, const int* in_sizes, int n_in,
                              void* d_out, int out_size, void* d_ws, size_t ws_size,
                              hipStream_t stream)
{
    const float* src1x = (const float*)d_in[0];   // [2,128,8,16,16]
    const float* dst2x = (const float*)d_in[1];   // [2,128,16,32,32]
    const float* w_off = (const float*)d_in[2];   // [648,256]
    const float* w_dcn = (const float*)d_in[3];   // [128,128,3,3,3]
    float* out = (float*)d_out;

    char* ws = (char*)d_ws;
    __half2* uph = (__half2*)(ws);                     // 8,388,608 B
    half8*   wox = (half8*)(ws + 8388608);             //   335,872 B
    half8*   wtx = (half8*)(ws + 8724480);             //   884,736 B
    float*   offs = (float*)(ws + 9609216);            // 84,934,656 B

    up_half_kernel<<<dim3((BB * GG * PP * 8) / 256), dim3(256), 0, stream>>>(
        src1x, uph);
    pack_wox_kernel<<<dim3(82), dim3(256), 0, stream>>>(w_off, wox);
    pack_wtx_kernel<<<dim3(216), dim3(256), 0, stream>>>(w_dcn, wtx);
    offset_mfma_kernel<<<dim3(PP / 64, BB), dim3(256), 0, stream>>>(
        dst2x, uph, wox, offs);
    fused_mfma_kernel<<<dim3(PP / 64, BB), dim3(256), 0, stream>>>(
        uph, offs, wtx, out);
}

// Round 3
// 335.951 us; speedup vs baseline: 4.0581x; 1.0584x over previous
//
#include <hip/hip_runtime.h>
#include <hip/hip_fp16.h>
#include <math.h>

// Problem constants
#define BB   2
#define CSN  128
#define CDN  128
#define SD   8
#define SH   16
#define SW   16
#define DD   16
#define DH   32
#define DW   32
#define PP   (DD*DH*DW)   // 16384
#define GG   8
#define K3   27
#define OO   648          // K3*3*G
#define MPAD 672          // offset GEMM M padded to 42 o-tiles
#define NT2  21           // o-tile pairs

typedef _Float16 half8 __attribute__((ext_vector_type(8)));
typedef float f32x4 __attribute__((ext_vector_type(4)));

template <int N> struct IC { static constexpr int v = N; };

// ---------------------------------------------------------------------------
// Kernel 1: trilinear upsample -> f16 channel-last  uph[b][g][p][16cc]
// ---------------------------------------------------------------------------
__global__ __launch_bounds__(256) void up_half_kernel(
    const float* __restrict__ src, __half2* __restrict__ uph)
{
    const int idx = blockIdx.x * 256 + threadIdx.x; // ((b*8+g)*PP+p)*8+ch
    const int ch = idx & 7;
    const int p  = (idx >> 3) & (PP - 1);
    const int bg = idx >> 17;
    const int g  = bg & 7, b = bg >> 3;
    const int zo = p >> 10, yo = (p >> 5) & 31, xo = p & 31;

    const float sz = 0.5f * (float)zo - 0.25f;
    const float sy = 0.5f * (float)yo - 0.25f;
    const float sx = 0.5f * (float)xo - 0.25f;
    const float zf = floorf(sz), yf = floorf(sy), xf = floorf(sx);
    const float fz = sz - zf, fy = sy - yf, fx = sx - xf;
    int z0 = (int)zf, y0 = (int)yf, x0 = (int)xf;
    int z1 = min(z0 + 1, SD - 1); z0 = max(z0, 0);
    int y1 = min(y0 + 1, SH - 1); y0 = max(y0, 0);
    int x1 = min(x0 + 1, SW - 1); x0 = max(x0, 0);

    const int c = g * 16 + ch * 2;
    float v[2];
#pragma unroll
    for (int cc = 0; cc < 2; ++cc) {
        const float* s = src + (size_t)(b * CSN + c + cc) * (SD * SH * SW);
        const float v000 = s[(z0 * SH + y0) * SW + x0];
        const float v001 = s[(z0 * SH + y0) * SW + x1];
        const float v010 = s[(z0 * SH + y1) * SW + x0];
        const float v011 = s[(z0 * SH + y1) * SW + x1];
        const float v100 = s[(z1 * SH + y0) * SW + x0];
        const float v101 = s[(z1 * SH + y0) * SW + x1];
        const float v110 = s[(z1 * SH + y1) * SW + x0];
        const float v111 = s[(z1 * SH + y1) * SW + x1];
        const float c00 = v000 + fx * (v001 - v000);
        const float c01 = v010 + fx * (v011 - v010);
        const float c10 = v100 + fx * (v101 - v100);
        const float c11 = v110 + fx * (v111 - v110);
        const float c0  = c00 + fy * (c01 - c00);
        const float c1  = c10 + fy * (c11 - c10);
        v[cc] = c0 + fz * (c1 - c0);
    }
    uph[idx] = __floats2half2_rn(v[0], v[1]);
}

// ---------------------------------------------------------------------------
// Kernel 2: pack w_offset -> wox f16 A-fragments, M padded to 672, x2 fold.
// half8 idx = (c0*MPAD + o)*4 + q
// ---------------------------------------------------------------------------
__global__ __launch_bounds__(256) void pack_wox_kernel(
    const float* __restrict__ wof, half8* __restrict__ wox)
{
    const int idx = blockIdx.x * 256 + threadIdx.x;   // 8*672*4 = 21504 total
    const int q = idx & 3;
    const int rest = idx >> 2;
    const int o = rest % MPAD;
    const int c0 = rest / MPAD;
    half8 h;
    if (o < OO) {
        const int c = c0 * 32 + q * 8;
        const float sc = (c >= 128) ? 2.0f : 1.0f;
        const float* wr = wof + (size_t)o * 256 + c;
#pragma unroll
        for (int j = 0; j < 8; ++j) h[j] = (_Float16)(wr[j] * sc);
    } else {
#pragma unroll
        for (int j = 0; j < 8; ++j) h[j] = (_Float16)0.0f;
    }
    wox[idx] = h;
}

// ---------------------------------------------------------------------------
// Kernel 3: pack w_dcn -> wtx f16 A-fragments per tap.
// half8 idx = ((k*4 + c0)*128 + o)*4 + q ; value = w_dcn[o][c0*32+q*8+j][k]
// ---------------------------------------------------------------------------
__global__ __launch_bounds__(256) void pack_wtx_kernel(
    const float* __restrict__ wdcn, half8* __restrict__ wtx)
{
    const int idx = blockIdx.x * 256 + threadIdx.x;   // 27*4*128*4 = 55296
    const int q  = idx & 3;
    const int o  = (idx >> 2) & 127;
    const int kc = idx >> 9;
    const int c0 = kc & 3;
    const int k  = kc >> 2;
    const int c  = c0 * 32 + q * 8;
    const float* wr = wdcn + ((size_t)o * CSN + c) * K3 + k;
    half8 h;
#pragma unroll
    for (int j = 0; j < 8; ++j) h[j] = (_Float16)wr[(size_t)j * K3];
    wtx[idx] = h;
}

// ---------------------------------------------------------------------------
// Kernel 4: offset 1x1 conv as f16 MFMA GEMM, grouped A-loads per iteration.
// ---------------------------------------------------------------------------
__global__ __launch_bounds__(256, 2) void offset_mfma_kernel(
    const float* __restrict__ dst, const __half2* __restrict__ uph,
    const half8* __restrict__ wox, float* __restrict__ offs)
{
    __shared__ half8 catx[32 * 64];    // [c-octet 32][p 64] -> 32 KiB
    const int tid = threadIdx.x;
    const int b = blockIdx.y;
    const int p0 = blockIdx.x * 64;

    // ---- stage cat tile (f16) ----
#pragma unroll
    for (int it = 0; it < 2; ++it) {
        const int t = tid + 256 * it;
        const int co = t >> 4, pq = t & 15;
        const int p = p0 + pq * 4;
        if (co < 16) {                       // dst rows, fp32 -> f16
            const int c = co * 8;
            const float* dp = dst + ((size_t)(b * CDN + c) << 14) + p;
            float vv[32];
#pragma unroll
            for (int j = 0; j < 8; ++j)
                *(float4*)&vv[j * 4] = *(const float4*)(dp + ((size_t)j << 14));
#pragma unroll
            for (int i = 0; i < 4; ++i) {
                half8 h;
#pragma unroll
                for (int j = 0; j < 8; ++j) h[j] = (_Float16)vv[j * 4 + i];
                catx[co * 64 + pq * 4 + i] = h;
            }
        } else {                             // upsampled rows: straight f16 copy
            const int g = (co - 16) >> 1, oct = (co - 16) & 1;
            const half8* up8 = (const half8*)uph;
            const size_t base = ((size_t)(b * GG + g) << 14);
#pragma unroll
            for (int i = 0; i < 4; ++i)
                catx[co * 64 + pq * 4 + i] = up8[(base + p + i) * 2 + oct];
        }
    }
    __syncthreads();

    const int w = tid >> 6, l = tid & 63, lo = l & 15, q = l >> 4;

    half8 Bf[8];
#pragma unroll
    for (int c0 = 0; c0 < 8; ++c0)
        Bf[c0] = catx[(c0 * 4 + q) * 64 + w * 16 + lo];

    const int p = p0 + w * 16 + lo;
#pragma unroll 1
    for (int ot2 = 0; ot2 < NT2; ++ot2) {
        const int ota = ot2 * 2, otb = ota + 1;
        half8 Aa[8], Ab[8];
#pragma unroll
        for (int c0 = 0; c0 < 8; ++c0) {
            Aa[c0] = wox[(size_t)(c0 * MPAD + ota * 16 + lo) * 4 + q];
            Ab[c0] = wox[(size_t)(c0 * MPAD + otb * 16 + lo) * 4 + q];
        }
        f32x4 aA = {0.f, 0.f, 0.f, 0.f}, aB = {0.f, 0.f, 0.f, 0.f};
#pragma unroll
        for (int c0 = 0; c0 < 8; ++c0) {
            aA = __builtin_amdgcn_mfma_f32_16x16x32_f16(Aa[c0], Bf[c0], aA, 0, 0, 0);
            aB = __builtin_amdgcn_mfma_f32_16x16x32_f16(Ab[c0], Bf[c0], aB, 0, 0, 0);
        }
#pragma unroll
        for (int r = 0; r < 4; ++r) {
            const int o = ota * 16 + q * 4 + r;
            if (o < OO) offs[((size_t)(b * OO + o) << 14) + p] = aA[r];
        }
#pragma unroll
        for (int r = 0; r < 4; ++r) {
            const int o = otb * 16 + q * 4 + r;
            if (o < OO) offs[((size_t)(b * OO + o) << 14) + p] = aB[r];
        }
    }
}

// ---------------------------------------------------------------------------
// Kernel 5: fused deformable sampling + MFMA contraction + ReLU.
// Branchless clamped gathers, double-buffered sampx, 1 barrier/tap,
// gathers + offs prefetched and overlapped with MFMA.
// ---------------------------------------------------------------------------
__global__ __launch_bounds__(256, 2) void fused_mfma_kernel(
    const __half2* __restrict__ uph, const float* __restrict__ offs,
    const half8* __restrict__ wtx, float* __restrict__ out)
{
    __shared__ half8 sampx[2][16 * 64];   // double-buffered, 32 KiB total
    const int tid = threadIdx.x;
    const int b = blockIdx.y;
    const int p0 = blockIdx.x * 64;
    const int w = tid >> 6, l = tid & 63, lo = l & 15, q = l >> 4;

    // sampling task identities: task t = tid + 256*it -> g = t>>6, tp = t&63
    const int g0 = tid >> 6, g1 = g0 + 4;
    const int tp = tid & 63;
    const int pA = p0 + tp;
    const int zoA = pA >> 10, yoA = (pA >> 5) & 31, xoA = pA & 31;

    f32x4 acc[2][4];
#pragma unroll
    for (int j = 0; j < 2; ++j)
#pragma unroll
        for (int pt = 0; pt < 4; ++pt) acc[j][pt] = (f32x4){0.f, 0.f, 0.f, 0.f};

    float offv[2][6];   // [parity][task*3 + comp], compile-time indexed only

    auto loadOffsP = [&](int k, float* dstv) {
        const size_t ob0 = ((size_t)(b * OO + g0 * 81 + k * 3) << 14) + pA;
        const size_t ob1 = ((size_t)(b * OO + g1 * 81 + k * 3) << 14) + pA;
        dstv[0] = offs[ob0];
        dstv[1] = offs[ob0 + PP];
        dstv[2] = offs[ob0 + 2 * PP];
        dstv[3] = offs[ob1];
        dstv[4] = offs[ob1 + PP];
        dstv[5] = offs[ob1 + 2 * PP];
    };

    // compute clamped corner addresses + weights, issue all 16 loads
    auto sampleSetup = [&](int g, int kz, int ky, int kx, const float* ofv,
                           float4* v, float* wc) {
        const float z = (float)(zoA + kz) + ofv[0];
        const float y = (float)(yoA + ky) + ofv[1];
        const float x = (float)(xoA + kx) + ofv[2];
        const float zf = floorf(z), yf = floorf(y), xf = floorf(x);
        const float fz = z - zf, fy = y - yf, fx = x - xf;
        const int z0 = (int)zf, y0 = (int)yf, x0 = (int)xf;
        int iz[2], iy[2], ix[2];
        float wz[2], wy[2], wx[2];
        iz[0] = min(max(z0, 0), DD - 1);
        iz[1] = min(max(z0 + 1, 0), DD - 1);
        wz[0] = (1.f - fz) * ((z0 >= 0 && z0 < DD) ? 1.f : 0.f);
        wz[1] = fz * ((z0 + 1 >= 0 && z0 + 1 < DD) ? 1.f : 0.f);
        iy[0] = min(max(y0, 0), DH - 1);
        iy[1] = min(max(y0 + 1, 0), DH - 1);
        wy[0] = (1.f - fy) * ((y0 >= 0 && y0 < DH) ? 1.f : 0.f);
        wy[1] = fy * ((y0 + 1 >= 0 && y0 + 1 < DH) ? 1.f : 0.f);
        ix[0] = min(max(x0, 0), DW - 1);
        ix[1] = min(max(x0 + 1, 0), DW - 1);
        wx[0] = (1.f - fx) * ((x0 >= 0 && x0 < DW) ? 1.f : 0.f);
        wx[1] = fx * ((x0 + 1 >= 0 && x0 + 1 < DW) ? 1.f : 0.f);
        const float4* base4 = (const float4*)(uph + ((size_t)(b * GG + g) << 17));
        int ci = 0;
#pragma unroll
        for (int dz = 0; dz < 2; ++dz)
#pragma unroll
            for (int dy = 0; dy < 2; ++dy)
#pragma unroll
                for (int dx = 0; dx < 2; ++dx) {
                    const int vox = (iz[dz] << 10) + (iy[dy] << 5) + ix[dx];
                    v[ci * 2]     = base4[(size_t)vox * 2];
                    v[ci * 2 + 1] = base4[(size_t)vox * 2 + 1];
                    wc[ci] = wz[dz] * wy[dy] * wx[dx];
                    ++ci;
                }
    };

    auto sampleFinish = [&](int g, const float4* v, const float* wc,
                            half8* dstbuf) {
        __align__(16) __half2 acch[8];
#pragma unroll
        for (int r = 0; r < 8; ++r) acch[r] = __floats2half2_rn(0.f, 0.f);
#pragma unroll
        for (int c = 0; c < 8; ++c) {
            const __half2 wh = __float2half2_rn(wc[c]);
            const __half2* h0 = (const __half2*)&v[2 * c];
            const __half2* h1 = (const __half2*)&v[2 * c + 1];
#pragma unroll
            for (int r = 0; r < 4; ++r) acch[r] = __hfma2(h0[r], wh, acch[r]);
#pragma unroll
            for (int r = 0; r < 4; ++r)
                acch[4 + r] = __hfma2(h1[r], wh, acch[4 + r]);
        }
        dstbuf[(g * 2) * 64 + tp]     = *(half8*)&acch[0];
        dstbuf[(g * 2 + 1) * 64 + tp] = *(half8*)&acch[4];
    };

    auto mfmaPart = [&](int c0base, const half8* Aa, const half8* Ab,
                        const half8* srcbuf) {
#pragma unroll
        for (int cc = 0; cc < 2; ++cc) {
            const int c0 = c0base + cc;
#pragma unroll
            for (int pt = 0; pt < 4; ++pt) {
                const half8 Bfr = srcbuf[(c0 * 4 + q) * 64 + pt * 16 + lo];
                acc[0][pt] = __builtin_amdgcn_mfma_f32_16x16x32_f16(
                    Aa[c0], Bfr, acc[0][pt], 0, 0, 0);
                acc[1][pt] = __builtin_amdgcn_mfma_f32_16x16x32_f16(
                    Ab[c0], Bfr, acc[1][pt], 0, 0, 0);
            }
        }
    };

    auto body = [&](int k, auto parc) {
        constexpr int PAR = decltype(parc)::v;      // k & 1
        const int kk = k + 1;
        const int kz = kk / 9 - 1, ky = (kk / 3) % 3 - 1, kx = kk % 3 - 1;
        const bool doS = (kk < K3);

        // A-fragments for tap k (issued first, longest to wait)
        half8 Aa[4], Ab[4];
#pragma unroll
        for (int c0 = 0; c0 < 4; ++c0) {
            Aa[c0] = wtx[(size_t)((k * 4 + c0) * 128 + (2 * w) * 16 + lo) * 4 + q];
            Ab[c0] = wtx[(size_t)((k * 4 + c0) * 128 + (2 * w + 1) * 16 + lo) * 4 + q];
        }

        float4 v0[16]; float wc0[8];
        if (doS) sampleSetup(g0, kz, ky, kx, &offv[PAR ^ 1][0], v0, wc0);

        mfmaPart(0, Aa, Ab, sampx[PAR]);

        if (doS) sampleFinish(g0, v0, wc0, sampx[PAR ^ 1]);

        float4 v1[16]; float wc1[8];
        if (doS) sampleSetup(g1, kz, ky, kx, &offv[PAR ^ 1][3], v1, wc1);

        mfmaPart(2, Aa, Ab, sampx[PAR]);

        if (doS) sampleFinish(g1, v1, wc1, sampx[PAR ^ 1]);

        if (k + 2 < K3) loadOffsP(k + 2, &offv[PAR][0]);
        __syncthreads();
    };

    // ---- prologue: sample tap 0 into buf 0, prefetch offs(1) ----
    loadOffsP(0, &offv[0][0]);
    {
        float4 v[16]; float wc[8];
        sampleSetup(g0, -1, -1, -1, &offv[0][0], v, wc);
        sampleFinish(g0, v, wc, sampx[0]);
        sampleSetup(g1, -1, -1, -1, &offv[0][3], v, wc);
        sampleFinish(g1, v, wc, sampx[0]);
    }
    loadOffsP(1, &offv[1][0]);
    __syncthreads();

#pragma unroll 1
    for (int k2 = 0; k2 < 13; ++k2) {
        body(2 * k2,     IC<0>{});
        body(2 * k2 + 1, IC<1>{});
    }
    body(26, IC<0>{});

    // ---- epilogue: ReLU + store ----
#pragma unroll
    for (int j = 0; j < 2; ++j) {
        const int o = (2 * w + j) * 16 + q * 4;
#pragma unroll
        for (int pt = 0; pt < 4; ++pt) {
#pragma unroll
            for (int r = 0; r < 4; ++r)
                out[((size_t)(b * CDN + o + r) << 14) + p0 + pt * 16 + lo] =
                    fmaxf(acc[j][pt][r], 0.f);
        }
    }
}

// ---------------------------------------------------------------------------
extern "C" void kernel_launch(void* const* d_in, const int* in_sizes, int n_in,
                              void* d_out, int out_size, void* d_ws, size_t ws_size,
                              hipStream_t stream)
{
    const float* src1x = (const float*)d_in[0];   // [2,128,8,16,16]
    const float* dst2x = (const float*)d_in[1];   // [2,128,16,32,32]
    const float* w_off = (const float*)d_in[2];   // [648,256]
    const float* w_dcn = (const float*)d_in[3];   // [128,128,3,3,3]
    float* out = (float*)d_out;

    char* ws = (char*)d_ws;
    __half2* uph = (__half2*)(ws);                     // 8,388,608 B
    half8*   wox = (half8*)(ws + 8388608);             //   344,064 B
    half8*   wtx = (half8*)(ws + 8732672);             //   884,736 B
    float*   offs = (float*)(ws + 9617408);            // 84,934,656 B

    up_half_kernel<<<dim3((BB * GG * PP * 8) / 256), dim3(256), 0, stream>>>(
        src1x, uph);
    pack_wox_kernel<<<dim3(84), dim3(256), 0, stream>>>(w_off, wox);
    pack_wtx_kernel<<<dim3(216), dim3(256), 0, stream>>>(w_dcn, wtx);
    offset_mfma_kernel<<<dim3(PP / 64, BB), dim3(256), 0, stream>>>(
        dst2x, uph, wox, offs);
    fused_mfma_kernel<<<dim3(PP / 64, BB), dim3(256), 0, stream>>>(
        uph, offs, wtx, out);
}

// Round 4
// 305.510 us; speedup vs baseline: 4.4624x; 1.0996x over previous
//
#include <hip/hip_runtime.h>
#include <hip/hip_fp16.h>
#include <math.h>

// Problem constants
#define BB   2
#define CSN  128
#define CDN  128
#define SD   8
#define SH   16
#define SW   16
#define DD   16
#define DH   32
#define DW   32
#define PP   (DD*DH*DW)   // 16384
#define GG   8
#define K3   27
#define OO   648          // K3*3*G
#define MPAD 672          // offset GEMM M padded to 42 o-tiles

typedef _Float16 half8 __attribute__((ext_vector_type(8)));
typedef float f32x4 __attribute__((ext_vector_type(4)));

// ---------------------------------------------------------------------------
// Kernel 1: trilinear upsample -> f16 channel-last  uph[b][g][p][16cc]
// ---------------------------------------------------------------------------
__global__ __launch_bounds__(256) void up_half_kernel(
    const float* __restrict__ src, __half2* __restrict__ uph)
{
    const int idx = blockIdx.x * 256 + threadIdx.x; // ((b*8+g)*PP+p)*8+ch
    const int ch = idx & 7;
    const int p  = (idx >> 3) & (PP - 1);
    const int bg = idx >> 17;
    const int g  = bg & 7, b = bg >> 3;
    const int zo = p >> 10, yo = (p >> 5) & 31, xo = p & 31;

    const float sz = 0.5f * (float)zo - 0.25f;
    const float sy = 0.5f * (float)yo - 0.25f;
    const float sx = 0.5f * (float)xo - 0.25f;
    const float zf = floorf(sz), yf = floorf(sy), xf = floorf(sx);
    const float fz = sz - zf, fy = sy - yf, fx = sx - xf;
    int z0 = (int)zf, y0 = (int)yf, x0 = (int)xf;
    int z1 = min(z0 + 1, SD - 1); z0 = max(z0, 0);
    int y1 = min(y0 + 1, SH - 1); y0 = max(y0, 0);
    int x1 = min(x0 + 1, SW - 1); x0 = max(x0, 0);

    const int c = g * 16 + ch * 2;
    float v[2];
#pragma unroll
    for (int cc = 0; cc < 2; ++cc) {
        const float* s = src + (size_t)(b * CSN + c + cc) * (SD * SH * SW);
        const float v000 = s[(z0 * SH + y0) * SW + x0];
        const float v001 = s[(z0 * SH + y0) * SW + x1];
        const float v010 = s[(z0 * SH + y1) * SW + x0];
        const float v011 = s[(z0 * SH + y1) * SW + x1];
        const float v100 = s[(z1 * SH + y0) * SW + x0];
        const float v101 = s[(z1 * SH + y0) * SW + x1];
        const float v110 = s[(z1 * SH + y1) * SW + x0];
        const float v111 = s[(z1 * SH + y1) * SW + x1];
        const float c00 = v000 + fx * (v001 - v000);
        const float c01 = v010 + fx * (v011 - v010);
        const float c10 = v100 + fx * (v101 - v100);
        const float c11 = v110 + fx * (v111 - v110);
        const float c0  = c00 + fy * (c01 - c00);
        const float c1  = c10 + fy * (c11 - c10);
        v[cc] = c0 + fz * (c1 - c0);
    }
    uph[idx] = __floats2half2_rn(v[0], v[1]);
}

// ---------------------------------------------------------------------------
// Kernel 2: pack w_offset -> wox f16 A-fragments, M padded to 672, x2 fold.
// half8 idx = (c0*MPAD + o)*4 + q
// ---------------------------------------------------------------------------
__global__ __launch_bounds__(256) void pack_wox_kernel(
    const float* __restrict__ wof, half8* __restrict__ wox)
{
    const int idx = blockIdx.x * 256 + threadIdx.x;   // 8*672*4 = 21504 total
    const int q = idx & 3;
    const int rest = idx >> 2;
    const int o = rest % MPAD;
    const int c0 = rest / MPAD;
    half8 h;
    if (o < OO) {
        const int c = c0 * 32 + q * 8;
        const float sc = (c >= 128) ? 2.0f : 1.0f;
        const float* wr = wof + (size_t)o * 256 + c;
#pragma unroll
        for (int j = 0; j < 8; ++j) h[j] = (_Float16)(wr[j] * sc);
    } else {
#pragma unroll
        for (int j = 0; j < 8; ++j) h[j] = (_Float16)0.0f;
    }
    wox[idx] = h;
}

// ---------------------------------------------------------------------------
// Kernel 3: pack w_dcn -> wtx f16 A-fragments per tap.
// half8 idx = ((k*4 + c0)*128 + o)*4 + q ; value = w_dcn[o][c0*32+q*8+j][k]
// ---------------------------------------------------------------------------
__global__ __launch_bounds__(256) void pack_wtx_kernel(
    const float* __restrict__ wdcn, half8* __restrict__ wtx)
{
    const int idx = blockIdx.x * 256 + threadIdx.x;   // 27*4*128*4 = 55296
    const int q  = idx & 3;
    const int o  = (idx >> 2) & 127;
    const int kc = idx >> 9;
    const int c0 = kc & 3;
    const int k  = kc >> 2;
    const int c  = c0 * 32 + q * 8;
    const float* wr = wdcn + ((size_t)o * CSN + c) * K3 + k;
    half8 h;
#pragma unroll
    for (int j = 0; j < 8; ++j) h[j] = (_Float16)wr[(size_t)j * K3];
    wtx[idx] = h;
}

// ---------------------------------------------------------------------------
// Kernel 4: offset 1x1 conv as f16 MFMA GEMM.  512 threads, 16 waves/CU.
// Wave w: p-subtile (w&3), o-half (w>>2) -> 21 o-tiles with A reg-prefetch.
// ---------------------------------------------------------------------------
__global__ __launch_bounds__(512, 4) void offset_mfma_kernel(
    const float* __restrict__ dst, const __half2* __restrict__ uph,
    const half8* __restrict__ wox, float* __restrict__ offs)
{
    __shared__ half8 catx[32 * 64];    // [c-octet 32][p 64] -> 32 KiB
    const int tid = threadIdx.x;
    const int b = blockIdx.y;
    const int p0 = blockIdx.x * 64;

    // ---- stage cat tile (f16): 512 tasks, 1 per thread ----
    {
        const int co = tid >> 4, pq = tid & 15;
        const int p = p0 + pq * 4;
        if (co < 16) {                       // dst rows, fp32 -> f16
            const int c = co * 8;
            const float* dp = dst + ((size_t)(b * CDN + c) << 14) + p;
            float vv[32];
#pragma unroll
            for (int j = 0; j < 8; ++j)
                *(float4*)&vv[j * 4] = *(const float4*)(dp + ((size_t)j << 14));
#pragma unroll
            for (int i = 0; i < 4; ++i) {
                half8 h;
#pragma unroll
                for (int j = 0; j < 8; ++j) h[j] = (_Float16)vv[j * 4 + i];
                catx[co * 64 + pq * 4 + i] = h;
            }
        } else {                             // upsampled rows: straight f16 copy
            const int g = (co - 16) >> 1, oct = (co - 16) & 1;
            const half8* up8 = (const half8*)uph;
            const size_t base = ((size_t)(b * GG + g) << 14);
#pragma unroll
            for (int i = 0; i < 4; ++i)
                catx[co * 64 + pq * 4 + i] = up8[(base + p + i) * 2 + oct];
        }
    }
    __syncthreads();

    const int w = tid >> 6, l = tid & 63, lo = l & 15, q = l >> 4;
    const int ps = w & 3;            // p-subtile
    const int half = w >> 2;         // o-half: tiles [half*21, half*21+21)

    half8 Bf[8];
#pragma unroll
    for (int c0 = 0; c0 < 8; ++c0)
        Bf[c0] = catx[(c0 * 4 + q) * 64 + ps * 16 + lo];

    const int p = p0 + ps * 16 + lo;
    const int otBase = half * 21;

    half8 Acur[8], Anxt[8];
#pragma unroll
    for (int c0 = 0; c0 < 8; ++c0)
        Acur[c0] = wox[(size_t)(c0 * MPAD + otBase * 16 + lo) * 4 + q];

#pragma unroll 1
    for (int i = 0; i < 21; ++i) {
        const int ot = otBase + i;
        const int otn = otBase + ((i < 20) ? (i + 1) : 20);
#pragma unroll
        for (int c0 = 0; c0 < 8; ++c0)
            Anxt[c0] = wox[(size_t)(c0 * MPAD + otn * 16 + lo) * 4 + q];

        f32x4 a = {0.f, 0.f, 0.f, 0.f};
#pragma unroll
        for (int c0 = 0; c0 < 8; ++c0)
            a = __builtin_amdgcn_mfma_f32_16x16x32_f16(Acur[c0], Bf[c0], a, 0, 0, 0);

#pragma unroll
        for (int r = 0; r < 4; ++r) {
            const int o = ot * 16 + q * 4 + r;
            if (o < OO) offs[((size_t)(b * OO + o) << 14) + p] = a[r];
        }
#pragma unroll
        for (int c0 = 0; c0 < 8; ++c0) Acur[c0] = Anxt[c0];
    }
}

// ---------------------------------------------------------------------------
// Kernel 5: fused deformable sampling + MFMA contraction + ReLU.
// 512 threads (16 waves/CU), 1 sampling task/thread, simple 2-barrier loop,
// branchless clamped gathers with incremental voxel addressing.
// ---------------------------------------------------------------------------
__global__ __launch_bounds__(512, 4) void fused_mfma_kernel(
    const __half2* __restrict__ uph, const float* __restrict__ offs,
    const half8* __restrict__ wtx, float* __restrict__ out)
{
    __shared__ half8 sampx[16 * 64];   // 16 KiB
    const int tid = threadIdx.x;
    const int b = blockIdx.y;
    const int p0 = blockIdx.x * 64;
    const int w = tid >> 6, l = tid & 63, lo = l & 15, q = l >> 4;

    // contraction mapping: wave w -> o-tiles {2(w&3), 2(w&3)+1},
    //                      p-subtiles {2(w>>2), 2(w>>2)+1}
    const int oT0 = (w & 3) * 2, oT1 = oT0 + 1;
    const int psA = (w >> 2) * 2, psB = psA + 1;

    // sampling task identity: g = tid>>6, tp = tid&63
    const int g  = tid >> 6;
    const int tp = tid & 63;
    const int pA = p0 + tp;
    const int zoA = pA >> 10, yoA = (pA >> 5) & 31, xoA = pA & 31;
    const float4* base4 = (const float4*)(uph + ((size_t)(b * GG + g) << 17));
    const size_t obBase = ((size_t)(b * OO + g * 81) << 14) + pA;

    f32x4 acc[2][2];
#pragma unroll
    for (int j = 0; j < 2; ++j)
#pragma unroll
        for (int pt = 0; pt < 2; ++pt) acc[j][pt] = (f32x4){0.f, 0.f, 0.f, 0.f};

#pragma unroll 1
    for (int k = 0; k < K3; ++k) {
        const int kz = k / 9 - 1;
        const int ky = (k / 3) % 3 - 1;
        const int kx = (k % 3) - 1;

        // ---- sampling phase ----
        {
            const size_t ob = obBase + (size_t)(k * 3) * PP;
            const float z = (float)(zoA + kz) + offs[ob];
            const float y = (float)(yoA + ky) + offs[ob + PP];
            const float x = (float)(xoA + kx) + offs[ob + 2 * PP];
            const float zf = floorf(z), yf = floorf(y), xf = floorf(x);
            const float fz = z - zf, fy = y - yf, fx = x - xf;
            const int z0i = (int)zf, y0i = (int)yf, x0i = (int)xf;

            const int iz0 = min(max(z0i, 0), DD - 1);
            const int iz1 = min(max(z0i + 1, 0), DD - 1);
            const int iy0 = min(max(y0i, 0), DH - 1);
            const int iy1 = min(max(y0i + 1, 0), DH - 1);
            const int ix0 = min(max(x0i, 0), DW - 1);
            const int ix1 = min(max(x0i + 1, 0), DW - 1);
            const float wz0 = ((unsigned)z0i < DD) ? 1.f - fz : 0.f;
            const float wz1 = ((unsigned)(z0i + 1) < DD) ? fz : 0.f;
            const float wy0 = ((unsigned)y0i < DH) ? 1.f - fy : 0.f;
            const float wy1 = ((unsigned)(y0i + 1) < DH) ? fy : 0.f;
            const float wx0 = ((unsigned)x0i < DW) ? 1.f - fx : 0.f;
            const float wx1 = ((unsigned)(x0i + 1) < DW) ? fx : 0.f;

            const int v000 = (iz0 << 10) + (iy0 << 5) + ix0;
            const int dzo = (iz1 - iz0) << 10;
            const int dyo = (iy1 - iy0) << 5;
            const int dxo = ix1 - ix0;
            const int vox[8] = {v000,             v000 + dxo,
                                v000 + dyo,       v000 + dyo + dxo,
                                v000 + dzo,       v000 + dzo + dxo,
                                v000 + dzo + dyo, v000 + dzo + dyo + dxo};
            const float wcs[8] = {wz0 * wy0 * wx0, wz0 * wy0 * wx1,
                                  wz0 * wy1 * wx0, wz0 * wy1 * wx1,
                                  wz1 * wy0 * wx0, wz1 * wy0 * wx1,
                                  wz1 * wy1 * wx0, wz1 * wy1 * wx1};

            __align__(16) __half2 acch[8];
#pragma unroll
            for (int r = 0; r < 8; ++r) acch[r] = __floats2half2_rn(0.f, 0.f);
#pragma unroll
            for (int ci = 0; ci < 8; ++ci) {
                const float4 u0 = base4[(size_t)(vox[ci] * 2)];
                const float4 u1 = base4[(size_t)(vox[ci] * 2 + 1)];
                const __half2 wh = __float2half2_rn(wcs[ci]);
                const __half2* h0 = (const __half2*)&u0;
                const __half2* h1 = (const __half2*)&u1;
#pragma unroll
                for (int r = 0; r < 4; ++r) acch[r] = __hfma2(h0[r], wh, acch[r]);
#pragma unroll
                for (int r = 0; r < 4; ++r)
                    acch[4 + r] = __hfma2(h1[r], wh, acch[4 + r]);
            }
            sampx[(g * 2) * 64 + tp]     = *(half8*)&acch[0];
            sampx[(g * 2 + 1) * 64 + tp] = *(half8*)&acch[4];
        }
        __syncthreads();

        // ---- MFMA contraction for this tap ----
#pragma unroll
        for (int c0 = 0; c0 < 4; ++c0) {
            const half8 Aa = wtx[(size_t)((k * 4 + c0) * 128 + oT0 * 16 + lo) * 4 + q];
            const half8 Ab = wtx[(size_t)((k * 4 + c0) * 128 + oT1 * 16 + lo) * 4 + q];
            const half8 B0 = sampx[(c0 * 4 + q) * 64 + psA * 16 + lo];
            const half8 B1 = sampx[(c0 * 4 + q) * 64 + psB * 16 + lo];
            acc[0][0] = __builtin_amdgcn_mfma_f32_16x16x32_f16(Aa, B0, acc[0][0], 0, 0, 0);
            acc[0][1] = __builtin_amdgcn_mfma_f32_16x16x32_f16(Aa, B1, acc[0][1], 0, 0, 0);
            acc[1][0] = __builtin_amdgcn_mfma_f32_16x16x32_f16(Ab, B0, acc[1][0], 0, 0, 0);
            acc[1][1] = __builtin_amdgcn_mfma_f32_16x16x32_f16(Ab, B1, acc[1][1], 0, 0, 0);
        }
        __syncthreads();
    }

    // ---- epilogue: ReLU + store ----
#pragma unroll
    for (int j = 0; j < 2; ++j) {
        const int oT = (j == 0) ? oT0 : oT1;
        const int o = oT * 16 + q * 4;
#pragma unroll
        for (int pt = 0; pt < 2; ++pt) {
            const int ps = (pt == 0) ? psA : psB;
#pragma unroll
            for (int r = 0; r < 4; ++r)
                out[((size_t)(b * CDN + o + r) << 14) + p0 + ps * 16 + lo] =
                    fmaxf(acc[j][pt][r], 0.f);
        }
    }
}

// ---------------------------------------------------------------------------
extern "C" void kernel_launch(void* const* d_in, const int* in_sizes, int n_in,
                              void* d_out, int out_size, void* d_ws, size_t ws_size,
                              hipStream_t stream)
{
    const float* src1x = (const float*)d_in[0];   // [2,128,8,16,16]
    const float* dst2x = (const float*)d_in[1];   // [2,128,16,32,32]
    const float* w_off = (const float*)d_in[2];   // [648,256]
    const float* w_dcn = (const float*)d_in[3];   // [128,128,3,3,3]
    float* out = (float*)d_out;

    char* ws = (char*)d_ws;
    __half2* uph = (__half2*)(ws);                     // 8,388,608 B
    half8*   wox = (half8*)(ws + 8388608);             //   344,064 B
    half8*   wtx = (half8*)(ws + 8732672);             //   884,736 B
    float*   offs = (float*)(ws + 9617408);            // 84,934,656 B

    up_half_kernel<<<dim3((BB * GG * PP * 8) / 256), dim3(256), 0, stream>>>(
        src1x, uph);
    pack_wox_kernel<<<dim3(84), dim3(256), 0, stream>>>(w_off, wox);
    pack_wtx_kernel<<<dim3(216), dim3(256), 0, stream>>>(w_dcn, wtx);
    offset_mfma_kernel<<<dim3(PP / 64, BB), dim3(512), 0, stream>>>(
        dst2x, uph, wox, offs);
    fused_mfma_kernel<<<dim3(PP / 64, BB), dim3(512), 0, stream>>>(
        uph, offs, wtx, out);
}

// Round 5
// 290.043 us; speedup vs baseline: 4.7004x; 1.0533x over previous
//
#include <hip/hip_runtime.h>
#include <hip/hip_fp16.h>
#include <math.h>

// Problem constants
#define BB   2
#define CSN  128
#define CDN  128
#define SD   8
#define SH   16
#define SW   16
#define DD   16
#define DH   32
#define DW   32
#define PP   (DD*DH*DW)   // 16384
#define GG   8
#define K3   27
#define OO   648          // K3*3*G
#define MPAD 672          // offset GEMM M padded to 42 o-tiles

typedef _Float16 half8 __attribute__((ext_vector_type(8)));
typedef float f32x4 __attribute__((ext_vector_type(4)));

// ---------------------------------------------------------------------------
// Kernel 1: trilinear upsample -> f16 half-plane layout uph[b][g][h][p][8ch]
// (h = channel half; voxel stride 16B so gather rows span half the lines)
// ---------------------------------------------------------------------------
__global__ __launch_bounds__(256) void up_half_kernel(
    const float* __restrict__ src, __half2* __restrict__ uph)
{
    const int idx = blockIdx.x * 256 + threadIdx.x; // (((b*8+g)*2+h)*PP+p)*4+c2
    const int c2 = idx & 3;
    const int p  = (idx >> 2) & (PP - 1);
    const int pl = idx >> 16;          // plane = (b*8+g)*2+h
    const int h  = pl & 1, g = (pl >> 1) & 7, b = pl >> 4;
    const int zo = p >> 10, yo = (p >> 5) & 31, xo = p & 31;

    const float sz = 0.5f * (float)zo - 0.25f;
    const float sy = 0.5f * (float)yo - 0.25f;
    const float sx = 0.5f * (float)xo - 0.25f;
    const float zf = floorf(sz), yf = floorf(sy), xf = floorf(sx);
    const float fz = sz - zf, fy = sy - yf, fx = sx - xf;
    int z0 = (int)zf, y0 = (int)yf, x0 = (int)xf;
    int z1 = min(z0 + 1, SD - 1); z0 = max(z0, 0);
    int y1 = min(y0 + 1, SH - 1); y0 = max(y0, 0);
    int x1 = min(x0 + 1, SW - 1); x0 = max(x0, 0);

    const int c = g * 16 + h * 8 + c2 * 2;
    float v[2];
#pragma unroll
    for (int cc = 0; cc < 2; ++cc) {
        const float* s = src + (size_t)(b * CSN + c + cc) * (SD * SH * SW);
        const float v000 = s[(z0 * SH + y0) * SW + x0];
        const float v001 = s[(z0 * SH + y0) * SW + x1];
        const float v010 = s[(z0 * SH + y1) * SW + x0];
        const float v011 = s[(z0 * SH + y1) * SW + x1];
        const float v100 = s[(z1 * SH + y0) * SW + x0];
        const float v101 = s[(z1 * SH + y0) * SW + x1];
        const float v110 = s[(z1 * SH + y1) * SW + x0];
        const float v111 = s[(z1 * SH + y1) * SW + x1];
        const float c00 = v000 + fx * (v001 - v000);
        const float c01 = v010 + fx * (v011 - v010);
        const float c10 = v100 + fx * (v101 - v100);
        const float c11 = v110 + fx * (v111 - v110);
        const float c0  = c00 + fy * (c01 - c00);
        const float c1  = c10 + fy * (c11 - c10);
        v[cc] = c0 + fz * (c1 - c0);
    }
    uph[idx] = __floats2half2_rn(v[0], v[1]);
}

// ---------------------------------------------------------------------------
// Kernel 2: pack w_offset -> wox f16 A-fragments, M padded to 672, x2 fold.
// half8 idx = (c0*MPAD + o)*4 + q
// ---------------------------------------------------------------------------
__global__ __launch_bounds__(256) void pack_wox_kernel(
    const float* __restrict__ wof, half8* __restrict__ wox)
{
    const int idx = blockIdx.x * 256 + threadIdx.x;   // 8*672*4 = 21504 total
    const int q = idx & 3;
    const int rest = idx >> 2;
    const int o = rest % MPAD;
    const int c0 = rest / MPAD;
    half8 h;
    if (o < OO) {
        const int c = c0 * 32 + q * 8;
        const float sc = (c >= 128) ? 2.0f : 1.0f;
        const float* wr = wof + (size_t)o * 256 + c;
#pragma unroll
        for (int j = 0; j < 8; ++j) h[j] = (_Float16)(wr[j] * sc);
    } else {
#pragma unroll
        for (int j = 0; j < 8; ++j) h[j] = (_Float16)0.0f;
    }
    wox[idx] = h;
}

// ---------------------------------------------------------------------------
// Kernel 3: pack w_dcn -> wtx f16 A-fragments per tap.
// half8 idx = ((k*4 + c0)*128 + o)*4 + q ; value = w_dcn[o][c0*32+q*8+j][k]
// ---------------------------------------------------------------------------
__global__ __launch_bounds__(256) void pack_wtx_kernel(
    const float* __restrict__ wdcn, half8* __restrict__ wtx)
{
    const int idx = blockIdx.x * 256 + threadIdx.x;   // 27*4*128*4 = 55296
    const int q  = idx & 3;
    const int o  = (idx >> 2) & 127;
    const int kc = idx >> 9;
    const int c0 = kc & 3;
    const int k  = kc >> 2;
    const int c  = c0 * 32 + q * 8;
    const float* wr = wdcn + ((size_t)o * CSN + c) * K3 + k;
    half8 h;
#pragma unroll
    for (int j = 0; j < 8; ++j) h[j] = (_Float16)wr[(size_t)j * K3];
    wtx[idx] = h;
}

// ---------------------------------------------------------------------------
// Kernel 4: offset 1x1 conv as f16 MFMA GEMM.  512 threads, 16 waves/CU.
// Wave w: p-subtile (w&3), o-half (w>>2); depth-1 A reg-prefetch; f16 output.
// ---------------------------------------------------------------------------
__global__ __launch_bounds__(512, 4) void offset_mfma_kernel(
    const float* __restrict__ dst, const float4* __restrict__ up4,
    const half8* __restrict__ wox, _Float16* __restrict__ offh)
{
    __shared__ half8 catx[32 * 64];    // [c-octet 32][p 64] -> 32 KiB
    const int tid = threadIdx.x;
    const int b = blockIdx.y;
    const int p0 = blockIdx.x * 64;

    // ---- stage cat tile (f16): 512 tasks, 1 per thread ----
    {
        const int co = tid >> 4, pq = tid & 15;
        const int p = p0 + pq * 4;
        if (co < 16) {                       // dst rows, fp32 -> f16
            const int c = co * 8;
            const float* dp = dst + ((size_t)(b * CDN + c) << 14) + p;
            float vv[32];
#pragma unroll
            for (int j = 0; j < 8; ++j)
                *(float4*)&vv[j * 4] = *(const float4*)(dp + ((size_t)j << 14));
#pragma unroll
            for (int i = 0; i < 4; ++i) {
                half8 h;
#pragma unroll
                for (int j = 0; j < 8; ++j) h[j] = (_Float16)vv[j * 4 + i];
                catx[co * 64 + pq * 4 + i] = h;
            }
        } else {                             // upsampled half-planes: f16 copy
            const int g = (co - 16) >> 1, oct = (co - 16) & 1;
            const size_t base = (size_t)((b * GG + g) * 2 + oct) << 14;
#pragma unroll
            for (int i = 0; i < 4; ++i) {
                const float4 u = up4[base + p + i];
                catx[co * 64 + pq * 4 + i] = *(const half8*)&u;
            }
        }
    }
    __syncthreads();

    const int w = tid >> 6, l = tid & 63, lo = l & 15, q = l >> 4;
    const int ps = w & 3;            // p-subtile
    const int half = w >> 2;         // o-half: tiles [half*21, half*21+21)

    half8 Bf[8];
#pragma unroll
    for (int c0 = 0; c0 < 8; ++c0)
        Bf[c0] = catx[(c0 * 4 + q) * 64 + ps * 16 + lo];

    const int p = p0 + ps * 16 + lo;
    const int otBase = half * 21;

    half8 Acur[8], Anxt[8];
#pragma unroll
    for (int c0 = 0; c0 < 8; ++c0)
        Acur[c0] = wox[(size_t)(c0 * MPAD + otBase * 16 + lo) * 4 + q];

#pragma unroll 1
    for (int i = 0; i < 21; ++i) {
        const int ot = otBase + i;
        const int otn = otBase + ((i < 20) ? (i + 1) : 20);
#pragma unroll
        for (int c0 = 0; c0 < 8; ++c0)
            Anxt[c0] = wox[(size_t)(c0 * MPAD + otn * 16 + lo) * 4 + q];

        f32x4 a = {0.f, 0.f, 0.f, 0.f};
#pragma unroll
        for (int c0 = 0; c0 < 8; ++c0)
            a = __builtin_amdgcn_mfma_f32_16x16x32_f16(Acur[c0], Bf[c0], a, 0, 0, 0);

#pragma unroll
        for (int r = 0; r < 4; ++r) {
            const int o = ot * 16 + q * 4 + r;
            if (o < OO) offh[((size_t)(b * OO + o) << 14) + p] = (_Float16)a[r];
        }
#pragma unroll
        for (int c0 = 0; c0 < 8; ++c0) Acur[c0] = Anxt[c0];
    }
}

// ---------------------------------------------------------------------------
// Kernel 5: fused deformable sampling + MFMA contraction + ReLU.
// 512 threads, 1 sampling task/thread (both channel halves), 2-barrier loop,
// branchless clamped gathers from 16B-stride half-planes.
// ---------------------------------------------------------------------------
__global__ __launch_bounds__(512, 4) void fused_mfma_kernel(
    const float4* __restrict__ up4, const _Float16* __restrict__ offh,
    const half8* __restrict__ wtx, float* __restrict__ out)
{
    __shared__ half8 sampx[16 * 64];   // 16 KiB
    const int tid = threadIdx.x;
    const int b = blockIdx.y;
    const int p0 = blockIdx.x * 64;
    const int w = tid >> 6, l = tid & 63, lo = l & 15, q = l >> 4;

    // contraction mapping: wave w -> o-tiles {2(w&3), 2(w&3)+1},
    //                      p-subtiles {2(w>>2), 2(w>>2)+1}
    const int oT0 = (w & 3) * 2, oT1 = oT0 + 1;
    const int psA = (w >> 2) * 2, psB = psA + 1;

    // sampling task identity: g = tid>>6, tp = tid&63 (thread does both h)
    const int g  = tid >> 6;
    const int tp = tid & 63;
    const int pA = p0 + tp;
    const int zoA = pA >> 10, yoA = (pA >> 5) & 31, xoA = pA & 31;
    const float4* baseH0 = up4 + ((size_t)((b * GG + g) * 2) << 14);
    const float4* baseH1 = baseH0 + (size_t)PP;
    const size_t obBase = ((size_t)(b * OO + g * 81) << 14) + pA;

    f32x4 acc[2][2];
#pragma unroll
    for (int j = 0; j < 2; ++j)
#pragma unroll
        for (int pt = 0; pt < 2; ++pt) acc[j][pt] = (f32x4){0.f, 0.f, 0.f, 0.f};

#pragma unroll 1
    for (int k = 0; k < K3; ++k) {
        const int kz = k / 9 - 1;
        const int ky = (k / 3) % 3 - 1;
        const int kx = (k % 3) - 1;

        // ---- sampling phase ----
        {
            const size_t ob = obBase + (size_t)(k * 3) * PP;
            const float z = (float)(zoA + kz) + (float)offh[ob];
            const float y = (float)(yoA + ky) + (float)offh[ob + PP];
            const float x = (float)(xoA + kx) + (float)offh[ob + 2 * PP];
            const float zf = floorf(z), yf = floorf(y), xf = floorf(x);
            const float fz = z - zf, fy = y - yf, fx = x - xf;
            const int z0i = (int)zf, y0i = (int)yf, x0i = (int)xf;

            const int iz0 = min(max(z0i, 0), DD - 1);
            const int iz1 = min(max(z0i + 1, 0), DD - 1);
            const int iy0 = min(max(y0i, 0), DH - 1);
            const int iy1 = min(max(y0i + 1, 0), DH - 1);
            const int ix0 = min(max(x0i, 0), DW - 1);
            const int ix1 = min(max(x0i + 1, 0), DW - 1);
            const float wz0 = ((unsigned)z0i < DD) ? 1.f - fz : 0.f;
            const float wz1 = ((unsigned)(z0i + 1) < DD) ? fz : 0.f;
            const float wy0 = ((unsigned)y0i < DH) ? 1.f - fy : 0.f;
            const float wy1 = ((unsigned)(y0i + 1) < DH) ? fy : 0.f;
            const float wx0 = ((unsigned)x0i < DW) ? 1.f - fx : 0.f;
            const float wx1 = ((unsigned)(x0i + 1) < DW) ? fx : 0.f;

            const int v000 = (iz0 << 10) + (iy0 << 5) + ix0;
            const int dzo = (iz1 - iz0) << 10;
            const int dyo = (iy1 - iy0) << 5;
            const int dxo = ix1 - ix0;
            const int vox[8] = {v000,             v000 + dxo,
                                v000 + dyo,       v000 + dyo + dxo,
                                v000 + dzo,       v000 + dzo + dxo,
                                v000 + dzo + dyo, v000 + dzo + dyo + dxo};
            const float wcs[8] = {wz0 * wy0 * wx0, wz0 * wy0 * wx1,
                                  wz0 * wy1 * wx0, wz0 * wy1 * wx1,
                                  wz1 * wy0 * wx0, wz1 * wy0 * wx1,
                                  wz1 * wy1 * wx0, wz1 * wy1 * wx1};

            __align__(16) __half2 acch[8];
#pragma unroll
            for (int r = 0; r < 8; ++r) acch[r] = __floats2half2_rn(0.f, 0.f);
#pragma unroll
            for (int ci = 0; ci < 8; ++ci) {
                const float4 u0 = baseH0[vox[ci]];
                const float4 u1 = baseH1[vox[ci]];
                const __half2 wh = __float2half2_rn(wcs[ci]);
                const __half2* h0 = (const __half2*)&u0;
                const __half2* h1 = (const __half2*)&u1;
#pragma unroll
                for (int r = 0; r < 4; ++r) acch[r] = __hfma2(h0[r], wh, acch[r]);
#pragma unroll
                for (int r = 0; r < 4; ++r)
                    acch[4 + r] = __hfma2(h1[r], wh, acch[4 + r]);
            }
            sampx[(g * 2) * 64 + tp]     = *(half8*)&acch[0];
            sampx[(g * 2 + 1) * 64 + tp] = *(half8*)&acch[4];
        }
        __syncthreads();

        // ---- MFMA contraction for this tap ----
#pragma unroll
        for (int c0 = 0; c0 < 4; ++c0) {
            const half8 Aa = wtx[(size_t)((k * 4 + c0) * 128 + oT0 * 16 + lo) * 4 + q];
            const half8 Ab = wtx[(size_t)((k * 4 + c0) * 128 + oT1 * 16 + lo) * 4 + q];
            const half8 B0 = sampx[(c0 * 4 + q) * 64 + psA * 16 + lo];
            const half8 B1 = sampx[(c0 * 4 + q) * 64 + psB * 16 + lo];
            acc[0][0] = __builtin_amdgcn_mfma_f32_16x16x32_f16(Aa, B0, acc[0][0], 0, 0, 0);
            acc[0][1] = __builtin_amdgcn_mfma_f32_16x16x32_f16(Aa, B1, acc[0][1], 0, 0, 0);
            acc[1][0] = __builtin_amdgcn_mfma_f32_16x16x32_f16(Ab, B0, acc[1][0], 0, 0, 0);
            acc[1][1] = __builtin_amdgcn_mfma_f32_16x16x32_f16(Ab, B1, acc[1][1], 0, 0, 0);
        }
        __syncthreads();
    }

    // ---- epilogue: ReLU + store ----
#pragma unroll
    for (int j = 0; j < 2; ++j) {
        const int oT = (j == 0) ? oT0 : oT1;
        const int o = oT * 16 + q * 4;
#pragma unroll
        for (int pt = 0; pt < 2; ++pt) {
            const int ps = (pt == 0) ? psA : psB;
#pragma unroll
            for (int r = 0; r < 4; ++r)
                out[((size_t)(b * CDN + o + r) << 14) + p0 + ps * 16 + lo] =
                    fmaxf(acc[j][pt][r], 0.f);
        }
    }
}

// ---------------------------------------------------------------------------
extern "C" void kernel_launch(void* const* d_in, const int* in_sizes, int n_in,
                              void* d_out, int out_size, void* d_ws, size_t ws_size,
                              hipStream_t stream)
{
    const float* src1x = (const float*)d_in[0];   // [2,128,8,16,16]
    const float* dst2x = (const float*)d_in[1];   // [2,128,16,32,32]
    const float* w_off = (const float*)d_in[2];   // [648,256]
    const float* w_dcn = (const float*)d_in[3];   // [128,128,3,3,3]
    float* out = (float*)d_out;

    char* ws = (char*)d_ws;
    __half2*  uph  = (__half2*)(ws);                   // 8,388,608 B
    half8*    wox  = (half8*)(ws + 8388608);           //   344,064 B
    half8*    wtx  = (half8*)(ws + 8732672);           //   884,736 B
    _Float16* offh = (_Float16*)(ws + 9617408);        // 42,467,328 B

    up_half_kernel<<<dim3(8192), dim3(256), 0, stream>>>(src1x, uph);
    pack_wox_kernel<<<dim3(84), dim3(256), 0, stream>>>(w_off, wox);
    pack_wtx_kernel<<<dim3(216), dim3(256), 0, stream>>>(w_dcn, wtx);
    offset_mfma_kernel<<<dim3(PP / 64, BB), dim3(512), 0, stream>>>(
        dst2x, (const float4*)uph, wox, offh);
    fused_mfma_kernel<<<dim3(PP / 64, BB), dim3(512), 0, stream>>>(
        (const float4*)uph, offh, wtx, out);
}

// Round 6
// 286.241 us; speedup vs baseline: 4.7628x; 1.0133x over previous
//
#include <hip/hip_runtime.h>
#include <hip/hip_fp16.h>
#include <math.h>

// Problem constants
#define BB   2
#define CSN  128
#define CDN  128
#define SD   8
#define SH   16
#define SW   16
#define DD   16
#define DH   32
#define DW   32
#define PP   (DD*DH*DW)   // 16384
#define GG   8
#define K3   27
#define OO   648          // K3*3*G

typedef _Float16 half8 __attribute__((ext_vector_type(8)));
typedef float f32x4 __attribute__((ext_vector_type(4)));

// ---------------------------------------------------------------------------
// Kernel 1: trilinear upsample via LDS slab.
// Block = (zo, plane=(b*8+g)*2+h). Stage src[8ch][2z][16y][16x] -> LDS
// channel-last, interpolate, store half8 rows coalesced.
// uph layout: [plane][p][8ch] f16 (16B per voxel) — same as R5.
// ---------------------------------------------------------------------------
__global__ __launch_bounds__(256) void up_slab_kernel(
    const float* __restrict__ src, half8* __restrict__ uph8)
{
    __shared__ float slab[2 * 16 * 16 * 8];   // [z2][y16][x16][ch8], 16 KiB
    const int zo = blockIdx.x;                // 0..15
    const int pl = blockIdx.y;                // (b*8+g)*2+h
    const int h = pl & 1, g = (pl >> 1) & 7, b = pl >> 4;
    const int tid = threadIdx.x;

    const int z0 = (zo - 1) >> 1;
    const float fz = (zo & 1) ? 0.25f : 0.75f;

    // ---- stage: thread = (zi, cc, y) row of 16 x-values ----
    {
        const int zi = tid >> 7, cc = (tid >> 4) & 7, y = tid & 15;
        const int zsrc = min(max(z0 + zi, 0), SD - 1);
        const float* srow = src +
            (((size_t)(b * CSN + g * 16 + h * 8 + cc) * SD + zsrc) * SH + y) * SW;
        const float4 r0 = *(const float4*)(srow);
        const float4 r1 = *(const float4*)(srow + 4);
        const float4 r2 = *(const float4*)(srow + 8);
        const float4 r3 = *(const float4*)(srow + 12);
        const float rr[16] = {r0.x, r0.y, r0.z, r0.w, r1.x, r1.y, r1.z, r1.w,
                              r2.x, r2.y, r2.z, r2.w, r3.x, r3.y, r3.z, r3.w};
        const int base = ((zi * 16 + y) * 16) * 8 + cc;
#pragma unroll
        for (int x = 0; x < 16; ++x) slab[base + x * 8] = rr[x];
    }
    __syncthreads();

    const float wz[2] = {1.f - fz, fz};
#pragma unroll 1
    for (int i = 0; i < 4; ++i) {
        const int pp = tid + i * 256;          // p within slice, lanes coalesced
        const int yo = pp >> 5, xo = pp & 31;
        const int y0 = (yo - 1) >> 1;
        const float fy = (yo & 1) ? 0.25f : 0.75f;
        const int y0c = max(y0, 0), y1c = min(y0 + 1, SH - 1);
        const int x0 = (xo - 1) >> 1;
        const float fx = (xo & 1) ? 0.25f : 0.75f;
        const int x0c = max(x0, 0), x1c = min(x0 + 1, SW - 1);
        const float wy[2] = {1.f - fy, fy};
        const float wx[2] = {1.f - fx, fx};
        const int ys[2] = {y0c, y1c};
        const int xs[2] = {x0c, x1c};

        float a[8];
#pragma unroll
        for (int c = 0; c < 8; ++c) a[c] = 0.f;
#pragma unroll
        for (int zi = 0; zi < 2; ++zi)
#pragma unroll
            for (int yi = 0; yi < 2; ++yi)
#pragma unroll
                for (int xi = 0; xi < 2; ++xi) {
                    const float wgt = wz[zi] * wy[yi] * wx[xi];
                    const float* cp =
                        &slab[((zi * 16 + ys[yi]) * 16 + xs[xi]) * 8];
                    const float4 v0 = *(const float4*)cp;
                    const float4 v1 = *(const float4*)(cp + 4);
                    a[0] = fmaf(wgt, v0.x, a[0]);
                    a[1] = fmaf(wgt, v0.y, a[1]);
                    a[2] = fmaf(wgt, v0.z, a[2]);
                    a[3] = fmaf(wgt, v0.w, a[3]);
                    a[4] = fmaf(wgt, v1.x, a[4]);
                    a[5] = fmaf(wgt, v1.y, a[5]);
                    a[6] = fmaf(wgt, v1.z, a[6]);
                    a[7] = fmaf(wgt, v1.w, a[7]);
                }
        half8 hv;
#pragma unroll
        for (int c = 0; c < 8; ++c) hv[c] = (_Float16)a[c];
        uph8[(size_t)pl * PP + zo * 1024 + pp] = hv;
    }
}

// ---------------------------------------------------------------------------
// Kernel 2: pack w_offset into group-rearranged f16 A-fragments.
// Groups: grp 0..5 = taps [4grp,4grp+4) (M=96, 6 tiles); grp 6 = taps 24..26
// (M=72 pad 80, 5 tiles). Row m -> (g = m/(3kt), kk, comp),
// o = (g*27 + grp*4 + kk)*3 + comp.  x2 fold on upsampled half of cat.
// half8 idx = grp*3072 + ((c0*nT + t)*16 + lo)*4 + q
// ---------------------------------------------------------------------------
__global__ __launch_bounds__(256) void pack_wox2_kernel(
    const float* __restrict__ wof, half8* __restrict__ wox2)
{
    const int idx = blockIdx.x * 256 + threadIdx.x;   // 20992 total
    const int grp = idx / 3072;                        // 0..6
    const int rem = idx - grp * 3072;
    const int nT = (grp < 6) ? 6 : 5;
    const int kt = (grp < 6) ? 4 : 3;
    const int c0 = rem / (nT * 64);
    const int rem2 = rem - c0 * (nT * 64);
    const int t = rem2 >> 6;
    const int lo = (rem2 >> 2) & 15;
    const int q = rem2 & 3;
    const int m = t * 16 + lo;

    half8 hv;
#pragma unroll
    for (int j = 0; j < 8; ++j) hv[j] = (_Float16)0.0f;
    if (m < kt * 24) {
        int g, r3;
        if (grp < 6) { g = m / 12; r3 = m - g * 12; }
        else         { g = m / 9;  r3 = m - g * 9; }
        const int kk = r3 / 3, comp = r3 - kk * 3;
        const int o = (g * K3 + grp * 4 + kk) * 3 + comp;
        const int c = c0 * 32 + q * 8;
        const float sc = (c >= 128) ? 2.0f : 1.0f;
        const float* wr = wof + (size_t)o * 256 + c;
#pragma unroll
        for (int j = 0; j < 8; ++j) hv[j] = (_Float16)(wr[j] * sc);
    }
    wox2[idx] = hv;
}

// ---------------------------------------------------------------------------
// Kernel 3: pack w_dcn -> wtx f16 A-fragments per tap.
// half8 idx = ((k*4 + c0)*128 + o)*4 + q ; value = w_dcn[o][c0*32+q*8+j][k]
// ---------------------------------------------------------------------------
__global__ __launch_bounds__(256) void pack_wtx_kernel(
    const float* __restrict__ wdcn, half8* __restrict__ wtx)
{
    const int idx = blockIdx.x * 256 + threadIdx.x;   // 55296
    const int q  = idx & 3;
    const int o  = (idx >> 2) & 127;
    const int kc = idx >> 9;
    const int c0 = kc & 3;
    const int k  = kc >> 2;
    const int c  = c0 * 32 + q * 8;
    const float* wr = wdcn + ((size_t)o * CSN + c) * K3 + k;
    half8 h;
#pragma unroll
    for (int j = 0; j < 8; ++j) h[j] = (_Float16)wr[(size_t)j * K3];
    wtx[idx] = h;
}

// ---------------------------------------------------------------------------
// Kernel 4: MEGA — offset mini-GEMM (per 4-tap group, into LDS) + deformable
// sampling + MFMA contraction + ReLU, all in one pass.
// 512 threads, LDS = catx 32K + sampx 16K + offls 24K = 72K (2 blocks/CU).
// ---------------------------------------------------------------------------
__global__ __launch_bounds__(512, 4) void mega_kernel(
    const float* __restrict__ dst, const float4* __restrict__ up4,
    const half8* __restrict__ wox2, const half8* __restrict__ wtx,
    float* __restrict__ out)
{
    __shared__ half8 catx[32 * 64];           // cat B-frags, 32 KiB
    __shared__ half8 sampx[16 * 64];          // samples,     16 KiB
    __shared__ float offls[4 * 8 * 3 * 64];   // offsets,     24 KiB

    const int tid = threadIdx.x;
    const int b = blockIdx.y;
    const int p0 = blockIdx.x * 64;

    // ---- stage cat tile (f16): 512 tasks, 1 per thread ----
    {
        const int co = tid >> 4, pq = tid & 15;
        const int p = p0 + pq * 4;
        if (co < 16) {                       // dst rows, fp32 -> f16
            const int c = co * 8;
            const float* dp = dst + ((size_t)(b * CDN + c) << 14) + p;
            float vv[32];
#pragma unroll
            for (int j = 0; j < 8; ++j)
                *(float4*)&vv[j * 4] = *(const float4*)(dp + ((size_t)j << 14));
#pragma unroll
            for (int i = 0; i < 4; ++i) {
                half8 h;
#pragma unroll
                for (int j = 0; j < 8; ++j) h[j] = (_Float16)vv[j * 4 + i];
                catx[co * 64 + pq * 4 + i] = h;
            }
        } else {                             // upsampled half-planes: f16 copy
            const int g = (co - 16) >> 1, oct = (co - 16) & 1;
            const size_t base = (size_t)((b * GG + g) * 2 + oct) * PP;
#pragma unroll
            for (int i = 0; i < 4; ++i) {
                const float4 u = up4[base + p + i];
                catx[co * 64 + pq * 4 + i] = *(const half8*)&u;
            }
        }
    }

    const int w = tid >> 6, l = tid & 63, lo = l & 15, q = l >> 4;
    // contraction mapping
    const int oT0 = (w & 3) * 2, oT1 = oT0 + 1;
    const int psA = (w >> 2) * 2, psB = psA + 1;
    // sampling task identity
    const int sg = tid >> 6;
    const int tp = tid & 63;
    const int pA = p0 + tp;
    const int zoA = pA >> 10, yoA = (pA >> 5) & 31, xoA = pA & 31;
    const float4* baseH0 = up4 + (size_t)((b * GG + sg) * 2) * PP;
    const float4* baseH1 = baseH0 + (size_t)PP;

    f32x4 acc[2][2];
#pragma unroll
    for (int j = 0; j < 2; ++j)
#pragma unroll
        for (int pt = 0; pt < 2; ++pt) acc[j][pt] = (f32x4){0.f, 0.f, 0.f, 0.f};

    __syncthreads();

#pragma unroll 1
    for (int grp = 0; grp < 7; ++grp) {
        const int kt = (grp < 6) ? 4 : 3;
        const int nT = (grp < 6) ? 6 : 5;
        const int nJobs = nT * 4;
        const half8* wg = wox2 + grp * 3072;

        // ---- phase A: offset mini-GEMM for this tap group -> offls ----
#pragma unroll 1
        for (int j = w; j < nJobs; j += 8) {
            const int ot = j >> 2, ps = j & 3;
            f32x4 a = {0.f, 0.f, 0.f, 0.f};
#pragma unroll
            for (int c0 = 0; c0 < 8; ++c0) {
                const half8 A = wg[(size_t)((c0 * nT + ot) * 16 + lo) * 4 + q];
                const half8 B = catx[(c0 * 4 + q) * 64 + ps * 16 + lo];
                a = __builtin_amdgcn_mfma_f32_16x16x32_f16(A, B, a, 0, 0, 0);
            }
#pragma unroll
            for (int r = 0; r < 4; ++r) {
                const int m = ot * 16 + q * 4 + r;
                if (m < kt * 24) {
                    int g, r3;
                    if (grp < 6) { g = m / 12; r3 = m - g * 12; }
                    else         { g = m / 9;  r3 = m - g * 9; }
                    const int kk = r3 / 3, comp = r3 - kk * 3;
                    offls[((kk * 8 + g) * 3 + comp) * 64 + ps * 16 + lo] = a[r];
                }
            }
        }
        __syncthreads();

        // ---- phase B: taps of this group ----
#pragma unroll 1
        for (int kk = 0; kk < kt; ++kk) {
            const int k = grp * 4 + kk;
            const int kz = k / 9 - 1;
            const int ky = (k / 3) % 3 - 1;
            const int kx = (k % 3) - 1;

            // sampling
            {
                const float z = (float)(zoA + kz) +
                                offls[((kk * 8 + sg) * 3 + 0) * 64 + tp];
                const float y = (float)(yoA + ky) +
                                offls[((kk * 8 + sg) * 3 + 1) * 64 + tp];
                const float x = (float)(xoA + kx) +
                                offls[((kk * 8 + sg) * 3 + 2) * 64 + tp];
                const float zf = floorf(z), yf = floorf(y), xf = floorf(x);
                const float fz = z - zf, fy = y - yf, fx = x - xf;
                const int z0i = (int)zf, y0i = (int)yf, x0i = (int)xf;

                const int iz0 = min(max(z0i, 0), DD - 1);
                const int iz1 = min(max(z0i + 1, 0), DD - 1);
                const int iy0 = min(max(y0i, 0), DH - 1);
                const int iy1 = min(max(y0i + 1, 0), DH - 1);
                const int ix0 = min(max(x0i, 0), DW - 1);
                const int ix1 = min(max(x0i + 1, 0), DW - 1);
                const float wz0 = ((unsigned)z0i < DD) ? 1.f - fz : 0.f;
                const float wz1 = ((unsigned)(z0i + 1) < DD) ? fz : 0.f;
                const float wy0 = ((unsigned)y0i < DH) ? 1.f - fy : 0.f;
                const float wy1 = ((unsigned)(y0i + 1) < DH) ? fy : 0.f;
                const float wx0 = ((unsigned)x0i < DW) ? 1.f - fx : 0.f;
                const float wx1 = ((unsigned)(x0i + 1) < DW) ? fx : 0.f;

                const int v000 = (iz0 << 10) + (iy0 << 5) + ix0;
                const int dzo = (iz1 - iz0) << 10;
                const int dyo = (iy1 - iy0) << 5;
                const int dxo = ix1 - ix0;
                const int vox[8] = {v000,             v000 + dxo,
                                    v000 + dyo,       v000 + dyo + dxo,
                                    v000 + dzo,       v000 + dzo + dxo,
                                    v000 + dzo + dyo, v000 + dzo + dyo + dxo};
                const float wcs[8] = {wz0 * wy0 * wx0, wz0 * wy0 * wx1,
                                      wz0 * wy1 * wx0, wz0 * wy1 * wx1,
                                      wz1 * wy0 * wx0, wz1 * wy0 * wx1,
                                      wz1 * wy1 * wx0, wz1 * wy1 * wx1};

                __align__(16) __half2 acch[8];
#pragma unroll
                for (int r = 0; r < 8; ++r) acch[r] = __floats2half2_rn(0.f, 0.f);
#pragma unroll
                for (int ci = 0; ci < 8; ++ci) {
                    const float4 u0 = baseH0[vox[ci]];
                    const float4 u1 = baseH1[vox[ci]];
                    const __half2 wh = __float2half2_rn(wcs[ci]);
                    const __half2* h0 = (const __half2*)&u0;
                    const __half2* h1 = (const __half2*)&u1;
#pragma unroll
                    for (int r = 0; r < 4; ++r)
                        acch[r] = __hfma2(h0[r], wh, acch[r]);
#pragma unroll
                    for (int r = 0; r < 4; ++r)
                        acch[4 + r] = __hfma2(h1[r], wh, acch[4 + r]);
                }
                sampx[(sg * 2) * 64 + tp]     = *(half8*)&acch[0];
                sampx[(sg * 2 + 1) * 64 + tp] = *(half8*)&acch[4];
            }
            __syncthreads();

            // contraction
#pragma unroll
            for (int c0 = 0; c0 < 4; ++c0) {
                const half8 Aa =
                    wtx[(size_t)((k * 4 + c0) * 128 + oT0 * 16 + lo) * 4 + q];
                const half8 Ab =
                    wtx[(size_t)((k * 4 + c0) * 128 + oT1 * 16 + lo) * 4 + q];
                const half8 B0 = sampx[(c0 * 4 + q) * 64 + psA * 16 + lo];
                const half8 B1 = sampx[(c0 * 4 + q) * 64 + psB * 16 + lo];
                acc[0][0] = __builtin_amdgcn_mfma_f32_16x16x32_f16(Aa, B0, acc[0][0], 0, 0, 0);
                acc[0][1] = __builtin_amdgcn_mfma_f32_16x16x32_f16(Aa, B1, acc[0][1], 0, 0, 0);
                acc[1][0] = __builtin_amdgcn_mfma_f32_16x16x32_f16(Ab, B0, acc[1][0], 0, 0, 0);
                acc[1][1] = __builtin_amdgcn_mfma_f32_16x16x32_f16(Ab, B1, acc[1][1], 0, 0, 0);
            }
            __syncthreads();
        }
    }

    // ---- epilogue: ReLU + store ----
#pragma unroll
    for (int j = 0; j < 2; ++j) {
        const int oT = (j == 0) ? oT0 : oT1;
        const int o = oT * 16 + q * 4;
#pragma unroll
        for (int pt = 0; pt < 2; ++pt) {
            const int ps = (pt == 0) ? psA : psB;
#pragma unroll
            for (int r = 0; r < 4; ++r)
                out[((size_t)(b * CDN + o + r) << 14) + p0 + ps * 16 + lo] =
                    fmaxf(acc[j][pt][r], 0.f);
        }
    }
}

// ---------------------------------------------------------------------------
extern "C" void kernel_launch(void* const* d_in, const int* in_sizes, int n_in,
                              void* d_out, int out_size, void* d_ws, size_t ws_size,
                              hipStream_t stream)
{
    const float* src1x = (const float*)d_in[0];   // [2,128,8,16,16]
    const float* dst2x = (const float*)d_in[1];   // [2,128,16,32,32]
    const float* w_off = (const float*)d_in[2];   // [648,256]
    const float* w_dcn = (const float*)d_in[3];   // [128,128,3,3,3]
    float* out = (float*)d_out;

    char* ws = (char*)d_ws;
    half8* uph8 = (half8*)(ws);                    // 8,388,608 B
    half8* wox2 = (half8*)(ws + 8388608);          //   335,872 B
    half8* wtx  = (half8*)(ws + 8724480);          //   884,736 B

    up_slab_kernel<<<dim3(DD, BB * GG * 2), dim3(256), 0, stream>>>(src1x, uph8);
    pack_wox2_kernel<<<dim3(82), dim3(256), 0, stream>>>(w_off, wox2);
    pack_wtx_kernel<<<dim3(216), dim3(256), 0, stream>>>(w_dcn, wtx);
    mega_kernel<<<dim3(PP / 64, BB), dim3(512), 0, stream>>>(
        dst2x, (const float4*)uph8, wox2, wtx, out);
}

// Round 7
// 268.493 us; speedup vs baseline: 5.0777x; 1.0661x over previous
//
#include <hip/hip_runtime.h>
#include <hip/hip_fp16.h>
#include <math.h>

// Problem constants
#define BB   2
#define CSN  128
#define CDN  128
#define SD   8
#define SH   16
#define SW   16
#define DD   16
#define DH   32
#define DW   32
#define PP   (DD*DH*DW)   // 16384
#define GG   8
#define K3   27
#define OO   648          // K3*3*G

typedef _Float16 half8 __attribute__((ext_vector_type(8)));
typedef float f32x4 __attribute__((ext_vector_type(4)));

// ---------------------------------------------------------------------------
// Kernel 1: trilinear upsample via channel-plane LDS slab (conflict-free).
// Block = (zo, plane=(b*8+g)*2+h). slab[zi][cc][y][17] fp32; staging writes
// are 2-way (free); interp = scalar ds reads; stores coalesced half8.
// uph layout: [plane][p][8ch] f16, 16B per voxel.
// ---------------------------------------------------------------------------
__global__ __launch_bounds__(256) void up_slab_kernel(
    const float* __restrict__ src, half8* __restrict__ uph8)
{
    __shared__ float slab[2 * 8 * 16 * 17];   // 17.4 KiB
    const int zo = blockIdx.x;                // 0..15
    const int pl = blockIdx.y;                // (b*8+g)*2+h
    const int h = pl & 1, g = (pl >> 1) & 7, b = pl >> 4;
    const int tid = threadIdx.x;

    const int z0 = (zo - 1) >> 1;
    const float fz = (zo & 1) ? 0.25f : 0.75f;

    // ---- stage: thread = (zi, cc, y) row of 16 x-values, 17-padded rows ----
    {
        const int zi = tid >> 7, cc = (tid >> 4) & 7, y = tid & 15;
        const int zsrc = min(max(z0 + zi, 0), SD - 1);
        const float* srow = src +
            (((size_t)(b * CSN + g * 16 + h * 8 + cc) * SD + zsrc) * SH + y) * SW;
        float* drow = &slab[((zi * 8 + cc) * 16 + y) * 17];
        *(float4*)(drow)      = *(const float4*)(srow);
        *(float4*)(drow + 4)  = *(const float4*)(srow + 4);
        *(float4*)(drow + 8)  = *(const float4*)(srow + 8);
        *(float4*)(drow + 12) = *(const float4*)(srow + 12);
    }
    __syncthreads();

    const float wz0 = 1.f - fz, wz1 = fz;
#pragma unroll 1
    for (int i = 0; i < 4; ++i) {
        const int pp = tid + i * 256;          // p within slice, coalesced
        const int yo = pp >> 5, xo = pp & 31;
        const int y0 = (yo - 1) >> 1;
        const float fy = (yo & 1) ? 0.25f : 0.75f;
        const int ys0 = max(y0, 0), ys1 = min(y0 + 1, SH - 1);
        const int x0 = (xo - 1) >> 1;
        const float fx = (xo & 1) ? 0.25f : 0.75f;
        const int xs0 = max(x0, 0), xs1 = min(x0 + 1, SW - 1);
        const float w00 = (1.f - fy) * (1.f - fx), w01 = (1.f - fy) * fx;
        const float w10 = fy * (1.f - fx),         w11 = fy * fx;
        const int a00 = ys0 * 17 + xs0, a01 = ys0 * 17 + xs1;
        const int a10 = ys1 * 17 + xs0, a11 = ys1 * 17 + xs1;

        half8 hv;
#pragma unroll
        for (int cc = 0; cc < 8; ++cc) {
            const float* p0 = &slab[(cc * 16) * 17];
            const float* p1 = &slab[((8 + cc) * 16) * 17];
            const float s0 = w00 * p0[a00] + w01 * p0[a01]
                           + w10 * p0[a10] + w11 * p0[a11];
            const float s1 = w00 * p1[a00] + w01 * p1[a01]
                           + w10 * p1[a10] + w11 * p1[a11];
            hv[cc] = (_Float16)(wz0 * s0 + wz1 * s1);
        }
        uph8[(size_t)pl * PP + zo * 1024 + pp] = hv;
    }
}

// ---------------------------------------------------------------------------
// Kernel 2: pack w_offset into group-rearranged f16 A-fragments.
// Groups: grp 0..5 = taps [4grp,4grp+4) (M=96, 6 tiles); grp 6 = taps 24..26
// (M=72 pad 80, 5 tiles). Row m -> (g, kk, comp),
// o = (g*27 + grp*4 + kk)*3 + comp.  x2 fold on upsampled half of cat.
// half8 idx = grp*3072 + ((c0*nT + t)*16 + lo)*4 + q
// ---------------------------------------------------------------------------
__global__ __launch_bounds__(256) void pack_wox2_kernel(
    const float* __restrict__ wof, half8* __restrict__ wox2)
{
    const int idx = blockIdx.x * 256 + threadIdx.x;   // 20992 total
    const int grp = idx / 3072;                        // 0..6
    const int rem = idx - grp * 3072;
    const int nT = (grp < 6) ? 6 : 5;
    const int kt = (grp < 6) ? 4 : 3;
    const int c0 = rem / (nT * 64);
    const int rem2 = rem - c0 * (nT * 64);
    const int t = rem2 >> 6;
    const int lo = (rem2 >> 2) & 15;
    const int q = rem2 & 3;
    const int m = t * 16 + lo;

    half8 hv;
#pragma unroll
    for (int j = 0; j < 8; ++j) hv[j] = (_Float16)0.0f;
    if (m < kt * 24) {
        int g, r3;
        if (grp < 6) { g = m / 12; r3 = m - g * 12; }
        else         { g = m / 9;  r3 = m - g * 9; }
        const int kk = r3 / 3, comp = r3 - kk * 3;
        const int o = (g * K3 + grp * 4 + kk) * 3 + comp;
        const int c = c0 * 32 + q * 8;
        const float sc = (c >= 128) ? 2.0f : 1.0f;
        const float* wr = wof + (size_t)o * 256 + c;
#pragma unroll
        for (int j = 0; j < 8; ++j) hv[j] = (_Float16)(wr[j] * sc);
    }
    wox2[idx] = hv;
}

// ---------------------------------------------------------------------------
// Kernel 3: pack w_dcn -> wtx f16 A-fragments per tap.
// half8 idx = ((k*4 + c0)*128 + o)*4 + q ; value = w_dcn[o][c0*32+q*8+j][k]
// ---------------------------------------------------------------------------
__global__ __launch_bounds__(256) void pack_wtx_kernel(
    const float* __restrict__ wdcn, half8* __restrict__ wtx)
{
    const int idx = blockIdx.x * 256 + threadIdx.x;   // 55296
    const int q  = idx & 3;
    const int o  = (idx >> 2) & 127;
    const int kc = idx >> 9;
    const int c0 = kc & 3;
    const int k  = kc >> 2;
    const int c  = c0 * 32 + q * 8;
    const float* wr = wdcn + ((size_t)o * CSN + c) * K3 + k;
    half8 h;
#pragma unroll
    for (int j = 0; j < 8; ++j) h[j] = (_Float16)wr[(size_t)j * K3];
    wtx[idx] = h;
}

// ---------------------------------------------------------------------------
// Kernel 4: MEGA — offset mini-GEMM (A reused across all 4 p-subtiles) +
// deformable sampling + MFMA contraction + ReLU.
// 512 threads; LDS = catx 32K + sampx 16K + offls 25.5K(stride 68) -> 2 blk/CU
// ---------------------------------------------------------------------------
#define OFFS_STRIDE 68

__global__ __launch_bounds__(512, 4) void mega_kernel(
    const float* __restrict__ dst, const float4* __restrict__ up4,
    const half8* __restrict__ wox2, const half8* __restrict__ wtx,
    float* __restrict__ out)
{
    __shared__ half8 catx[32 * 64];                    // cat B-frags, 32 KiB
    __shared__ half8 sampx[16 * 64];                   // samples,     16 KiB
    __shared__ float offls[4 * 8 * 3 * OFFS_STRIDE];   // offsets,   25.5 KiB

    const int tid = threadIdx.x;
    const int b = blockIdx.y;
    const int p0 = blockIdx.x * 64;

    // ---- stage cat tile (f16): 512 tasks, 1 per thread ----
    {
        const int co = tid >> 4, pq = tid & 15;
        const int p = p0 + pq * 4;
        if (co < 16) {                       // dst rows, fp32 -> f16
            const int c = co * 8;
            const float* dp = dst + ((size_t)(b * CDN + c) << 14) + p;
            float vv[32];
#pragma unroll
            for (int j = 0; j < 8; ++j)
                *(float4*)&vv[j * 4] = *(const float4*)(dp + ((size_t)j << 14));
#pragma unroll
            for (int i = 0; i < 4; ++i) {
                half8 h;
#pragma unroll
                for (int j = 0; j < 8; ++j) h[j] = (_Float16)vv[j * 4 + i];
                catx[co * 64 + pq * 4 + i] = h;
            }
        } else {                             // upsampled half-planes: f16 copy
            const int g = (co - 16) >> 1, oct = (co - 16) & 1;
            const size_t base = (size_t)((b * GG + g) * 2 + oct) * PP;
#pragma unroll
            for (int i = 0; i < 4; ++i) {
                const float4 u = up4[base + p + i];
                catx[co * 64 + pq * 4 + i] = *(const half8*)&u;
            }
        }
    }

    const int w = tid >> 6, l = tid & 63, lo = l & 15, q = l >> 4;
    // contraction mapping
    const int oT0 = (w & 3) * 2, oT1 = oT0 + 1;
    const int psA = (w >> 2) * 2, psB = psA + 1;
    // sampling task identity
    const int sg = tid >> 6;
    const int tp = tid & 63;
    const int pA = p0 + tp;
    const int zoA = pA >> 10, yoA = (pA >> 5) & 31, xoA = pA & 31;
    const float4* baseH0 = up4 + (size_t)((b * GG + sg) * 2) * PP;
    const float4* baseH1 = baseH0 + (size_t)PP;

    f32x4 acc[2][2];
#pragma unroll
    for (int j = 0; j < 2; ++j)
#pragma unroll
        for (int pt = 0; pt < 2; ++pt) acc[j][pt] = (f32x4){0.f, 0.f, 0.f, 0.f};

    __syncthreads();

#pragma unroll 1
    for (int grp = 0; grp < 7; ++grp) {
        const int kt = (grp < 6) ? 4 : 3;
        const int nT = (grp < 6) ? 6 : 5;
        const half8* wg = wox2 + grp * 3072;

        // ---- phase A: offset mini-GEMM. Wave w owns o-tile w, ALL 4 ps ----
        if (w < nT) {
            const int ot = w;
            f32x4 a[4];
#pragma unroll
            for (int ps = 0; ps < 4; ++ps) a[ps] = (f32x4){0.f, 0.f, 0.f, 0.f};
#pragma unroll
            for (int c0 = 0; c0 < 8; ++c0) {
                const half8 A = wg[(size_t)((c0 * nT + ot) * 16 + lo) * 4 + q];
#pragma unroll
                for (int ps = 0; ps < 4; ++ps) {
                    const half8 B = catx[(c0 * 4 + q) * 64 + ps * 16 + lo];
                    a[ps] = __builtin_amdgcn_mfma_f32_16x16x32_f16(A, B, a[ps], 0, 0, 0);
                }
            }
#pragma unroll
            for (int ps = 0; ps < 4; ++ps) {
#pragma unroll
                for (int r = 0; r < 4; ++r) {
                    const int m = ot * 16 + q * 4 + r;
                    if (m < kt * 24) {
                        int g, r3;
                        if (grp < 6) { g = m / 12; r3 = m - g * 12; }
                        else         { g = m / 9;  r3 = m - g * 9; }
                        const int kk = r3 / 3, comp = r3 - kk * 3;
                        offls[((kk * 8 + g) * 3 + comp) * OFFS_STRIDE +
                              ps * 16 + lo] = a[ps][r];
                    }
                }
            }
        }
        __syncthreads();

        // ---- phase B: taps of this group ----
#pragma unroll 1
        for (int kk = 0; kk < kt; ++kk) {
            const int k = grp * 4 + kk;
            const int kz = k / 9 - 1;
            const int ky = (k / 3) % 3 - 1;
            const int kx = (k % 3) - 1;

            // sampling
            {
                const float z = (float)(zoA + kz) +
                    offls[((kk * 8 + sg) * 3 + 0) * OFFS_STRIDE + tp];
                const float y = (float)(yoA + ky) +
                    offls[((kk * 8 + sg) * 3 + 1) * OFFS_STRIDE + tp];
                const float x = (float)(xoA + kx) +
                    offls[((kk * 8 + sg) * 3 + 2) * OFFS_STRIDE + tp];
                const float zf = floorf(z), yf = floorf(y), xf = floorf(x);
                const float fz = z - zf, fy = y - yf, fx = x - xf;
                const int z0i = (int)zf, y0i = (int)yf, x0i = (int)xf;

                const int iz0 = min(max(z0i, 0), DD - 1);
                const int iz1 = min(max(z0i + 1, 0), DD - 1);
                const int iy0 = min(max(y0i, 0), DH - 1);
                const int iy1 = min(max(y0i + 1, 0), DH - 1);
                const int ix0 = min(max(x0i, 0), DW - 1);
                const int ix1 = min(max(x0i + 1, 0), DW - 1);
                const float wz0 = ((unsigned)z0i < DD) ? 1.f - fz : 0.f;
                const float wz1 = ((unsigned)(z0i + 1) < DD) ? fz : 0.f;
                const float wy0 = ((unsigned)y0i < DH) ? 1.f - fy : 0.f;
                const float wy1 = ((unsigned)(y0i + 1) < DH) ? fy : 0.f;
                const float wx0 = ((unsigned)x0i < DW) ? 1.f - fx : 0.f;
                const float wx1 = ((unsigned)(x0i + 1) < DW) ? fx : 0.f;

                const int v000 = (iz0 << 10) + (iy0 << 5) + ix0;
                const int dzo = (iz1 - iz0) << 10;
                const int dyo = (iy1 - iy0) << 5;
                const int dxo = ix1 - ix0;
                const int vox[8] = {v000,             v000 + dxo,
                                    v000 + dyo,       v000 + dyo + dxo,
                                    v000 + dzo,       v000 + dzo + dxo,
                                    v000 + dzo + dyo, v000 + dzo + dyo + dxo};
                const float wcs[8] = {wz0 * wy0 * wx0, wz0 * wy0 * wx1,
                                      wz0 * wy1 * wx0, wz0 * wy1 * wx1,
                                      wz1 * wy0 * wx0, wz1 * wy0 * wx1,
                                      wz1 * wy1 * wx0, wz1 * wy1 * wx1};

                __align__(16) __half2 acch[8];
#pragma unroll
                for (int r = 0; r < 8; ++r) acch[r] = __floats2half2_rn(0.f, 0.f);
#pragma unroll
                for (int ci = 0; ci < 8; ++ci) {
                    const float4 u0 = baseH0[vox[ci]];
                    const float4 u1 = baseH1[vox[ci]];
                    const __half2 wh = __float2half2_rn(wcs[ci]);
                    const __half2* h0 = (const __half2*)&u0;
                    const __half2* h1 = (const __half2*)&u1;
#pragma unroll
                    for (int r = 0; r < 4; ++r)
                        acch[r] = __hfma2(h0[r], wh, acch[r]);
#pragma unroll
                    for (int r = 0; r < 4; ++r)
                        acch[4 + r] = __hfma2(h1[r], wh, acch[4 + r]);
                }
                sampx[(sg * 2) * 64 + tp]     = *(half8*)&acch[0];
                sampx[(sg * 2 + 1) * 64 + tp] = *(half8*)&acch[4];
            }
            __syncthreads();

            // contraction
#pragma unroll
            for (int c0 = 0; c0 < 4; ++c0) {
                const half8 Aa =
                    wtx[(size_t)((k * 4 + c0) * 128 + oT0 * 16 + lo) * 4 + q];
                const half8 Ab =
                    wtx[(size_t)((k * 4 + c0) * 128 + oT1 * 16 + lo) * 4 + q];
                const half8 B0 = sampx[(c0 * 4 + q) * 64 + psA * 16 + lo];
                const half8 B1 = sampx[(c0 * 4 + q) * 64 + psB * 16 + lo];
                acc[0][0] = __builtin_amdgcn_mfma_f32_16x16x32_f16(Aa, B0, acc[0][0], 0, 0, 0);
                acc[0][1] = __builtin_amdgcn_mfma_f32_16x16x32_f16(Aa, B1, acc[0][1], 0, 0, 0);
                acc[1][0] = __builtin_amdgcn_mfma_f32_16x16x32_f16(Ab, B0, acc[1][0], 0, 0, 0);
                acc[1][1] = __builtin_amdgcn_mfma_f32_16x16x32_f16(Ab, B1, acc[1][1], 0, 0, 0);
            }
            __syncthreads();
        }
    }

    // ---- epilogue: ReLU + store ----
#pragma unroll
    for (int j = 0; j < 2; ++j) {
        const int oT = (j == 0) ? oT0 : oT1;
        const int o = oT * 16 + q * 4;
#pragma unroll
        for (int pt = 0; pt < 2; ++pt) {
            const int ps = (pt == 0) ? psA : psB;
#pragma unroll
            for (int r = 0; r < 4; ++r)
                out[((size_t)(b * CDN + o + r) << 14) + p0 + ps * 16 + lo] =
                    fmaxf(acc[j][pt][r], 0.f);
        }
    }
}

// ---------------------------------------------------------------------------
extern "C" void kernel_launch(void* const* d_in, const int* in_sizes, int n_in,
                              void* d_out, int out_size, void* d_ws, size_t ws_size,
                              hipStream_t stream)
{
    const float* src1x = (const float*)d_in[0];   // [2,128,8,16,16]
    const float* dst2x = (const float*)d_in[1];   // [2,128,16,32,32]
    const float* w_off = (const float*)d_in[2];   // [648,256]
    const float* w_dcn = (const float*)d_in[3];   // [128,128,3,3,3]
    float* out = (float*)d_out;

    char* ws = (char*)d_ws;
    half8* uph8 = (half8*)(ws);                    // 8,388,608 B
    half8* wox2 = (half8*)(ws + 8388608);          //   335,872 B
    half8* wtx  = (half8*)(ws + 8724480);          //   884,736 B

    up_slab_kernel<<<dim3(DD, BB * GG * 2), dim3(256), 0, stream>>>(src1x, uph8);
    pack_wox2_kernel<<<dim3(82), dim3(256), 0, stream>>>(w_off, wox2);
    pack_wtx_kernel<<<dim3(216), dim3(256), 0, stream>>>(w_dcn, wtx);
    mega_kernel<<<dim3(PP / 64, BB), dim3(512), 0, stream>>>(
        dst2x, (const float4*)uph8, wox2, wtx, out);
}

// Round 8
// 257.968 us; speedup vs baseline: 5.2848x; 1.0408x over previous
//
#include <hip/hip_runtime.h>
#include <hip/hip_fp16.h>
#include <math.h>

// Problem constants
#define BB   2
#define CSN  128
#define CDN  128
#define SD   8
#define SH   16
#define SW   16
#define DD   16
#define DH   32
#define DW   32
#define PP   (DD*DH*DW)   // 16384
#define GG   8
#define K3   27
#define OO   648          // K3*3*G

typedef _Float16 half8 __attribute__((ext_vector_type(8)));
typedef float f32x4 __attribute__((ext_vector_type(4)));

// ---------------------------------------------------------------------------
// Kernel 1: PREP — fused upsample + both weight packs (one dispatch).
// blocks [0,512): trilinear upsample via channel-plane LDS slab
// blocks [512,594): pack w_offset -> wox2 (group-rearranged A-frags, x2 fold)
// blocks [594,810): pack w_dcn -> wtx (per-tap A-frags)
// ---------------------------------------------------------------------------
__global__ __launch_bounds__(256) void prep_kernel(
    const float* __restrict__ src, const float* __restrict__ wof,
    const float* __restrict__ wdcn, half8* __restrict__ uph8,
    half8* __restrict__ wox2, half8* __restrict__ wtx)
{
    __shared__ float slab[2 * 8 * 16 * 17];   // 17.4 KiB (upsample branch only)
    const int bid = blockIdx.x;
    const int tid = threadIdx.x;

    if (bid < 512) {
        // ---- trilinear upsample, plane (b,g,h), z-slice zo ----
        const int zo = bid & 15, pl = bid >> 4;
        const int h = pl & 1, g = (pl >> 1) & 7, b = pl >> 4;
        const int z0 = (zo - 1) >> 1;
        const float fz = (zo & 1) ? 0.25f : 0.75f;
        {
            const int zi = tid >> 7, cc = (tid >> 4) & 7, y = tid & 15;
            const int zsrc = min(max(z0 + zi, 0), SD - 1);
            const float* srow = src +
                (((size_t)(b * CSN + g * 16 + h * 8 + cc) * SD + zsrc) * SH + y) * SW;
            float* drow = &slab[((zi * 8 + cc) * 16 + y) * 17];
            *(float4*)(drow)      = *(const float4*)(srow);
            *(float4*)(drow + 4)  = *(const float4*)(srow + 4);
            *(float4*)(drow + 8)  = *(const float4*)(srow + 8);
            *(float4*)(drow + 12) = *(const float4*)(srow + 12);
        }
        __syncthreads();

        const float wz0 = 1.f - fz, wz1 = fz;
#pragma unroll 1
        for (int i = 0; i < 4; ++i) {
            const int pp = tid + i * 256;
            const int yo = pp >> 5, xo = pp & 31;
            const int y0 = (yo - 1) >> 1;
            const float fy = (yo & 1) ? 0.25f : 0.75f;
            const int ys0 = max(y0, 0), ys1 = min(y0 + 1, SH - 1);
            const int x0 = (xo - 1) >> 1;
            const float fx = (xo & 1) ? 0.25f : 0.75f;
            const int xs0 = max(x0, 0), xs1 = min(x0 + 1, SW - 1);
            const float w00 = (1.f - fy) * (1.f - fx), w01 = (1.f - fy) * fx;
            const float w10 = fy * (1.f - fx),         w11 = fy * fx;
            const int a00 = ys0 * 17 + xs0, a01 = ys0 * 17 + xs1;
            const int a10 = ys1 * 17 + xs0, a11 = ys1 * 17 + xs1;

            half8 hv;
#pragma unroll
            for (int cc = 0; cc < 8; ++cc) {
                const float* p0 = &slab[(cc * 16) * 17];
                const float* p1 = &slab[((8 + cc) * 16) * 17];
                const float s0 = w00 * p0[a00] + w01 * p0[a01]
                               + w10 * p0[a10] + w11 * p0[a11];
                const float s1 = w00 * p1[a00] + w01 * p1[a01]
                               + w10 * p1[a10] + w11 * p1[a11];
                hv[cc] = (_Float16)(wz0 * s0 + wz1 * s1);
            }
            uph8[(size_t)pl * PP + zo * 1024 + pp] = hv;
        }
    } else if (bid < 594) {
        // ---- pack w_offset: grp 0..5 taps 4grp..4grp+3 (nT=6); grp6 (nT=5)
        const int idx = (bid - 512) * 256 + tid;   // < 20992
        const int grp = idx / 3072;
        const int rem = idx - grp * 3072;
        const int nT = (grp < 6) ? 6 : 5;
        const int kt = (grp < 6) ? 4 : 3;
        const int c0 = rem / (nT * 64);
        const int rem2 = rem - c0 * (nT * 64);
        const int t = rem2 >> 6;
        const int lo = (rem2 >> 2) & 15;
        const int q = rem2 & 3;
        const int m = t * 16 + lo;

        half8 hv;
#pragma unroll
        for (int j = 0; j < 8; ++j) hv[j] = (_Float16)0.0f;
        if (m < kt * 24) {
            int g, r3;
            if (grp < 6) { g = m / 12; r3 = m - g * 12; }
            else         { g = m / 9;  r3 = m - g * 9; }
            const int kk = r3 / 3, comp = r3 - kk * 3;
            const int o = (g * K3 + grp * 4 + kk) * 3 + comp;
            const int c = c0 * 32 + q * 8;
            const float sc = (c >= 128) ? 2.0f : 1.0f;
            const float* wr = wof + (size_t)o * 256 + c;
#pragma unroll
            for (int j = 0; j < 8; ++j) hv[j] = (_Float16)(wr[j] * sc);
        }
        wox2[idx] = hv;
    } else {
        // ---- pack w_dcn: half8 idx = ((k*4+c0)*128+o)*4+q ----
        const int idx = (bid - 594) * 256 + tid;   // < 55296
        const int q  = idx & 3;
        const int o  = (idx >> 2) & 127;
        const int kc = idx >> 9;
        const int c0 = kc & 3;
        const int k  = kc >> 2;
        const int c  = c0 * 32 + q * 8;
        const float* wr = wdcn + ((size_t)o * CSN + c) * K3 + k;
        half8 h;
#pragma unroll
        for (int j = 0; j < 8; ++j) h[j] = (_Float16)wr[(size_t)j * K3];
        wtx[idx] = h;
    }
}

// ---------------------------------------------------------------------------
// Kernel 2: MEGA — all offsets upfront (phase A, one pass) then one
// uninterrupted 27-tap pipelined sample+MFMA run (1 barrier/tap, sampx dbuf
// aliased over dead catx). LDS = 32K (catx|sampx dbuf) + 81K offls = 113 KB.
// ---------------------------------------------------------------------------
#define LDS_TOTAL (32768 + 82944)

__global__ __launch_bounds__(512, 2) void mega_kernel(
    const float* __restrict__ dst, const float4* __restrict__ up4,
    const half8* __restrict__ wox2, const half8* __restrict__ wtx,
    float* __restrict__ out)
{
    __shared__ __align__(16) char ldsraw[LDS_TOTAL];
    half8* catx = (half8*)ldsraw;                       // 32 KiB (phase 0/A)
    half8* sampx = (half8*)ldsraw;                      // dbuf 2x16 KiB (phase B)
    _Float16* offls = (_Float16*)(ldsraw + 32768);      // 648 rows x 64, 81 KiB

    const int tid = threadIdx.x;
    const int b = blockIdx.y;
    const int p0 = blockIdx.x * 64;

    // ---- phase 0: stage cat tile (f16) ----
    {
        const int co = tid >> 4, pq = tid & 15;
        const int p = p0 + pq * 4;
        if (co < 16) {                       // dst rows, fp32 -> f16
            const int c = co * 8;
            const float* dp = dst + ((size_t)(b * CDN + c) << 14) + p;
            float vv[32];
#pragma unroll
            for (int j = 0; j < 8; ++j)
                *(float4*)&vv[j * 4] = *(const float4*)(dp + ((size_t)j << 14));
#pragma unroll
            for (int i = 0; i < 4; ++i) {
                half8 h;
#pragma unroll
                for (int j = 0; j < 8; ++j) h[j] = (_Float16)vv[j * 4 + i];
                catx[co * 64 + pq * 4 + i] = h;
            }
        } else {                             // upsampled half-planes: f16 copy
            const int g = (co - 16) >> 1, oct = (co - 16) & 1;
            const size_t base = (size_t)((b * GG + g) * 2 + oct) * PP;
#pragma unroll
            for (int i = 0; i < 4; ++i) {
                const float4 u = up4[base + p + i];
                catx[co * 64 + pq * 4 + i] = *(const half8*)&u;
            }
        }
    }

    const int w = tid >> 6, l = tid & 63, lo = l & 15, q = l >> 4;
    const int oT0 = (w & 3) * 2, oT1 = oT0 + 1;
    const int psA = (w >> 2) * 2, psB = psA + 1;
    const int sg = tid >> 6;
    const int tp = tid & 63;
    const int pA = p0 + tp;
    const int zoA = pA >> 10, yoA = (pA >> 5) & 31, xoA = pA & 31;
    const float4* baseH0 = up4 + (size_t)((b * GG + sg) * 2) * PP;
    const float4* baseH1 = baseH0 + (size_t)PP;

    __syncthreads();

    // ---- phase A: ALL offsets upfront. 41 o-tiles round-robin over waves ----
#pragma unroll 1
    for (int t = w; t < 41; t += 8) {
        int grp, ot, nT, kt;
        if (t < 36) { grp = t / 6; ot = t - (t / 6) * 6; nT = 6; kt = 4; }
        else        { grp = 6;     ot = t - 36;          nT = 5; kt = 3; }
        const half8* wg = wox2 + grp * 3072;
        f32x4 a[4];
#pragma unroll
        for (int ps = 0; ps < 4; ++ps) a[ps] = (f32x4){0.f, 0.f, 0.f, 0.f};
#pragma unroll
        for (int c0 = 0; c0 < 8; ++c0) {
            const half8 A = wg[(size_t)((c0 * nT + ot) * 16 + lo) * 4 + q];
#pragma unroll
            for (int ps = 0; ps < 4; ++ps) {
                const half8 B = catx[(c0 * 4 + q) * 64 + ps * 16 + lo];
                a[ps] = __builtin_amdgcn_mfma_f32_16x16x32_f16(A, B, a[ps], 0, 0, 0);
            }
        }
#pragma unroll
        for (int ps = 0; ps < 4; ++ps) {
#pragma unroll
            for (int r = 0; r < 4; ++r) {
                const int m = ot * 16 + q * 4 + r;
                if (m < kt * 24) {
                    int g, r3;
                    if (grp < 6) { g = m / 12; r3 = m - g * 12; }
                    else         { g = m / 9;  r3 = m - g * 9; }
                    const int kk = r3 / 3, comp = r3 - kk * 3;
                    const int k = grp * 4 + kk;
                    offls[((k * 8 + g) * 3 + comp) * 64 + ps * 16 + lo] =
                        (_Float16)a[ps][r];
                }
            }
        }
    }
    __syncthreads();
    // catx is dead from here; sampx dbuf aliases its storage.

    f32x4 acc[2][2];
#pragma unroll
    for (int j = 0; j < 2; ++j)
#pragma unroll
        for (int pt = 0; pt < 2; ++pt) acc[j][pt] = (f32x4){0.f, 0.f, 0.f, 0.f};

    // sampling helpers
    auto sampleSetup = [&](int k, float4* v, float* wcs) {
        const int kz = k / 9 - 1;
        const int ky = (k / 3) % 3 - 1;
        const int kx = (k % 3) - 1;
        const int rbase = (k * 8 + sg) * 3;
        const float z = (float)(zoA + kz) + (float)offls[(rbase + 0) * 64 + tp];
        const float y = (float)(yoA + ky) + (float)offls[(rbase + 1) * 64 + tp];
        const float x = (float)(xoA + kx) + (float)offls[(rbase + 2) * 64 + tp];
        const float zf = floorf(z), yf = floorf(y), xf = floorf(x);
        const float fz = z - zf, fy = y - yf, fx = x - xf;
        const int z0i = (int)zf, y0i = (int)yf, x0i = (int)xf;

        const int iz0 = min(max(z0i, 0), DD - 1);
        const int iz1 = min(max(z0i + 1, 0), DD - 1);
        const int iy0 = min(max(y0i, 0), DH - 1);
        const int iy1 = min(max(y0i + 1, 0), DH - 1);
        const int ix0 = min(max(x0i, 0), DW - 1);
        const int ix1 = min(max(x0i + 1, 0), DW - 1);
        const float wz0 = ((unsigned)z0i < DD) ? 1.f - fz : 0.f;
        const float wz1 = ((unsigned)(z0i + 1) < DD) ? fz : 0.f;
        const float wy0 = ((unsigned)y0i < DH) ? 1.f - fy : 0.f;
        const float wy1 = ((unsigned)(y0i + 1) < DH) ? fy : 0.f;
        const float wx0 = ((unsigned)x0i < DW) ? 1.f - fx : 0.f;
        const float wx1 = ((unsigned)(x0i + 1) < DW) ? fx : 0.f;

        const int v000 = (iz0 << 10) + (iy0 << 5) + ix0;
        const int dzo = (iz1 - iz0) << 10;
        const int dyo = (iy1 - iy0) << 5;
        const int dxo = ix1 - ix0;
        const int vox[8] = {v000,             v000 + dxo,
                            v000 + dyo,       v000 + dyo + dxo,
                            v000 + dzo,       v000 + dzo + dxo,
                            v000 + dzo + dyo, v000 + dzo + dyo + dxo};
        wcs[0] = wz0 * wy0 * wx0; wcs[1] = wz0 * wy0 * wx1;
        wcs[2] = wz0 * wy1 * wx0; wcs[3] = wz0 * wy1 * wx1;
        wcs[4] = wz1 * wy0 * wx0; wcs[5] = wz1 * wy0 * wx1;
        wcs[6] = wz1 * wy1 * wx0; wcs[7] = wz1 * wy1 * wx1;
#pragma unroll
        for (int ci = 0; ci < 8; ++ci) {
            v[ci * 2]     = baseH0[vox[ci]];
            v[ci * 2 + 1] = baseH1[vox[ci]];
        }
    };
    auto sampleFinish = [&](const float4* v, const float* wcs, half8* dstbuf) {
        __align__(16) __half2 acch[8];
#pragma unroll
        for (int r = 0; r < 8; ++r) acch[r] = __floats2half2_rn(0.f, 0.f);
#pragma unroll
        for (int ci = 0; ci < 8; ++ci) {
            const __half2 wh = __float2half2_rn(wcs[ci]);
            const __half2* h0 = (const __half2*)&v[ci * 2];
            const __half2* h1 = (const __half2*)&v[ci * 2 + 1];
#pragma unroll
            for (int r = 0; r < 4; ++r) acch[r] = __hfma2(h0[r], wh, acch[r]);
#pragma unroll
            for (int r = 0; r < 4; ++r)
                acch[4 + r] = __hfma2(h1[r], wh, acch[4 + r]);
        }
        dstbuf[(sg * 2) * 64 + tp]     = *(half8*)&acch[0];
        dstbuf[(sg * 2 + 1) * 64 + tp] = *(half8*)&acch[4];
    };

    // ---- prologue: sample tap 0 into buf 0 ----
    {
        float4 v[16]; float wcs[8];
        sampleSetup(0, v, wcs);
        sampleFinish(v, wcs, sampx);
    }
    __syncthreads();

    // ---- phase B: 27 taps, 1 barrier/tap, gathers overlap MFMA ----
#pragma unroll 1
    for (int k = 0; k < K3; ++k) {
        half8* bufC = sampx + (k & 1) * 1024;
        half8* bufP = sampx + ((k & 1) ^ 1) * 1024;

        // issue next tap's gathers first (longest latency)
        float4 v[16]; float wcs[8];
        const bool doS = (k + 1 < K3);
        if (doS) sampleSetup(k + 1, v, wcs);

        // A-fragments for tap k
        half8 Aa[4], Ab[4];
#pragma unroll
        for (int c0 = 0; c0 < 4; ++c0) {
            Aa[c0] = wtx[(size_t)((k * 4 + c0) * 128 + oT0 * 16 + lo) * 4 + q];
            Ab[c0] = wtx[(size_t)((k * 4 + c0) * 128 + oT1 * 16 + lo) * 4 + q];
        }

        // MFMA contraction for tap k (hides the in-flight gathers)
#pragma unroll
        for (int c0 = 0; c0 < 4; ++c0) {
            const half8 B0 = bufC[(c0 * 4 + q) * 64 + psA * 16 + lo];
            const half8 B1 = bufC[(c0 * 4 + q) * 64 + psB * 16 + lo];
            acc[0][0] = __builtin_amdgcn_mfma_f32_16x16x32_f16(Aa[c0], B0, acc[0][0], 0, 0, 0);
            acc[0][1] = __builtin_amdgcn_mfma_f32_16x16x32_f16(Aa[c0], B1, acc[0][1], 0, 0, 0);
            acc[1][0] = __builtin_amdgcn_mfma_f32_16x16x32_f16(Ab[c0], B0, acc[1][0], 0, 0, 0);
            acc[1][1] = __builtin_amdgcn_mfma_f32_16x16x32_f16(Ab[c0], B1, acc[1][1], 0, 0, 0);
        }

        if (doS) sampleFinish(v, wcs, bufP);
        __syncthreads();
    }

    // ---- epilogue: ReLU + store ----
#pragma unroll
    for (int j = 0; j < 2; ++j) {
        const int oT = (j == 0) ? oT0 : oT1;
        const int o = oT * 16 + q * 4;
#pragma unroll
        for (int pt = 0; pt < 2; ++pt) {
            const int ps = (pt == 0) ? psA : psB;
#pragma unroll
            for (int r = 0; r < 4; ++r)
                out[((size_t)(b * CDN + o + r) << 14) + p0 + ps * 16 + lo] =
                    fmaxf(acc[j][pt][r], 0.f);
        }
    }
}

// ---------------------------------------------------------------------------
extern "C" void kernel_launch(void* const* d_in, const int* in_sizes, int n_in,
                              void* d_out, int out_size, void* d_ws, size_t ws_size,
                              hipStream_t stream)
{
    const float* src1x = (const float*)d_in[0];   // [2,128,8,16,16]
    const float* dst2x = (const float*)d_in[1];   // [2,128,16,32,32]
    const float* w_off = (const float*)d_in[2];   // [648,256]
    const float* w_dcn = (const float*)d_in[3];   // [128,128,3,3,3]
    float* out = (float*)d_out;

    char* ws = (char*)d_ws;
    half8* uph8 = (half8*)(ws);                    // 8,388,608 B
    half8* wox2 = (half8*)(ws + 8388608);          //   335,872 B
    half8* wtx  = (half8*)(ws + 8724480);          //   884,736 B

    prep_kernel<<<dim3(810), dim3(256), 0, stream>>>(
        src1x, w_off, w_dcn, uph8, wox2, wtx);
    mega_kernel<<<dim3(PP / 64, BB), dim3(512), 0, stream>>>(
        dst2x, (const float4*)uph8, wox2, wtx, out);
}